// Round 14
// baseline (106.517 us; speedup 1.0000x reference)
//
#include <hip/hip_runtime.h>
#include <hip/hip_bf16.h>
#include <stdint.h>

#define N_NODES 16384   // B*H*W
#define NPB     4096    // nodes per batch
#define NB      4
#define KNN     4
#define NEDGE   (N_NODES * 5)
#define WIN     12      // sorted-order window radius for exact 1-D kNN
#define NBUK    4096

typedef short bf16x8 __attribute__((ext_vector_type(8)));
typedef float f32x4 __attribute__((ext_vector_type(4)));
typedef unsigned short u16x8 __attribute__((ext_vector_type(8)));

__device__ __forceinline__ unsigned short f2bf(float f) {
  unsigned u = __float_as_uint(f);
  unsigned r = (u + 0x7fff + ((u >> 16) & 1)) >> 16;   // RNE
  return (unsigned short)r;
}
__device__ __forceinline__ float bf2f(unsigned short u) {
  return __uint_as_float(((unsigned)u) << 16);
}

// ---- fused bucket stage: hist + scan + scatter + deg-init, one block/batch ----
__global__ __launch_bounds__(1024)
void bucket_kernel(const float* __restrict__ dm,
                   unsigned long long* __restrict__ tmpkeys,
                   int* __restrict__ bstart_g, int* __restrict__ deg) {
  __shared__ int sHist[4096];
  __shared__ int sStart[4096];
  __shared__ int sCur[4096];
  __shared__ int part1[1024];
  __shared__ int part2[64];
  const int t = threadIdx.x, b = blockIdx.x;
  const float* d = dm + b * NPB;
  unsigned long long kv[4]; int bk[4];
#pragma unroll
  for (int r = 0; r < 4; ++r) {
    int i = t + r * 1024;
    sHist[i] = 0;
    deg[b * NPB + i] = 1;
  }
  __syncthreads();
#pragma unroll
  for (int r = 0; r < 4; ++r) {
    int i = t + r * 1024;
    float v = d[i];
    kv[r] = (((unsigned long long)__float_as_uint(v)) << 32) | (unsigned)i;
    int k = (int)(v * (float)NBUK); if (k > NBUK - 1) k = NBUK - 1;
    bk[r] = k;
    atomicAdd(&sHist[k], 1);
  }
  __syncthreads();
  part1[t] = sHist[4 * t] + sHist[4 * t + 1] + sHist[4 * t + 2] + sHist[4 * t + 3];
  __syncthreads();
  if (t < 64) {
    int s = 0;
#pragma unroll
    for (int k = 0; k < 16; ++k) s += part1[16 * t + k];
    part2[t] = s;
  }
  __syncthreads();
  if (t == 0) {
    int a = 0;
    for (int u = 0; u < 64; ++u) { int v = part2[u]; part2[u] = a; a += v; }
  }
  __syncthreads();
  {
    int base = part2[t >> 4];
    for (int k = (t >> 4) * 16; k < t; ++k) base += part1[k];
#pragma unroll
    for (int q = 0; q < 4; ++q) {
      int i = 4 * t + q;
      sStart[i] = base; sCur[i] = base;
      base += sHist[i];
    }
  }
  __syncthreads();
#pragma unroll
  for (int r = 0; r < 4; ++r) {
    int slot = atomicAdd(&sCur[bk[r]], 1);
    tmpkeys[b * NPB + slot] = kv[r];
  }
#pragma unroll
  for (int r = 0; r < 4; ++r) {
    int i = t + r * 1024;
    bstart_g[b * NPB + i] = b * NPB + sStart[i];
  }
  if (b == NB - 1 && t == 0) bstart_g[N_NODES] = N_NODES;
}

// ---- finalize: exact (value,idx) order within bucket ----
__global__ void bfinal_kernel(const unsigned long long* __restrict__ tmpkeys,
                              const int* __restrict__ bstart,
                              unsigned long long* __restrict__ skeys) {
  int g = blockIdx.x * 256 + threadIdx.x;   // global bucket id
  if (g >= N_NODES) return;
  int s0 = bstart[g], s1 = bstart[g + 1];
  int cnt = s1 - s0;
  if (cnt <= 0) return;
  if (cnt == 1) { skeys[s0] = tmpkeys[s0]; return; }
  for (int i = s0; i < s1; ++i) {
    unsigned long long ki = tmpkeys[i];
    int r = 0;
    for (int j = s0; j < s1; ++j) r += (tmpkeys[j] < ki);
    skeys[s0 + r] = ki;
  }
}

// ---- kNN select driven by sorted position ----
__global__ void knn_select_kernel(const unsigned long long* __restrict__ skeys,
                                  int* __restrict__ tgt, int* __restrict__ deg) {
  int p = blockIdx.x * 256 + threadIdx.x;   // global sorted slot
  if (p >= N_NODES) return;
  int b = p >> 12, pl = p & (NPB - 1);
  const unsigned long long* sk = skeys + b * NPB;
  unsigned long long kp = sk[pl];
  float di = __uint_as_float((unsigned)(kp >> 32));
  int node = b * NPB + (int)(kp & 0xffffffffull);
  int lo = pl - WIN; if (lo < 0) lo = 0;
  int hi = pl + WIN; if (hi > NPB - 1) hi = NPB - 1;
  unsigned long long k0 = ~0ull, k1 = ~0ull, k2 = ~0ull, k3 = ~0ull, k4 = ~0ull;
  for (int q = lo; q <= hi; ++q) {
    unsigned long long key = sk[q];
    float v = __uint_as_float((unsigned)(key >> 32));
    float dist = fabsf(di - v);
    unsigned long long dk = (((unsigned long long)__float_as_uint(dist)) << 32) |
                            (key & 0xffffffffull);
    if (dk < k4) {
      if (dk < k0)      { k4 = k3; k3 = k2; k2 = k1; k1 = k0; k0 = dk; }
      else if (dk < k1) { k4 = k3; k3 = k2; k2 = k1; k1 = dk; }
      else if (dk < k2) { k4 = k3; k3 = k2; k2 = dk; }
      else if (dk < k3) { k4 = k3; k3 = dk; }
      else              { k4 = dk; }
    }
  }
  int base = b * NPB;
  int t0 = base + (int)(k1 & 0xffffffffull);
  int t1 = base + (int)(k2 & 0xffffffffull);
  int t2 = base + (int)(k3 & 0xffffffffull);
  int t3 = base + (int)(k4 & 0xffffffffull);
  tgt[node * KNN + 0] = t0; atomicAdd(&deg[t0], 1);
  tgt[node * KNN + 1] = t1; atomicAdd(&deg[t1], 1);
  tgt[node * KNN + 2] = t2; atomicAdd(&deg[t2], 1);
  tgt[node * KNN + 3] = t3; atomicAdd(&deg[t3], 1);
}

// ---- dinv + exclusive scan of deg (single block) ----
__global__ void scan_kernel(const int* __restrict__ deg, float* __restrict__ dinv,
                            int* __restrict__ off, int* __restrict__ cur) {
  __shared__ int part[256];
  int t = threadIdx.x;
  int base = t * 64;
  int s = 0;
  for (int i = 0; i < 64; ++i) s += deg[base + i];
  part[t] = s;
  __syncthreads();
  if (t == 0) {
    int acc = 0;
    for (int i = 0; i < 256; ++i) { int v = part[i]; part[i] = acc; acc += v; }
  }
  __syncthreads();
  int acc = part[t];
  for (int i = 0; i < 64; ++i) {
    int dg = deg[base + i];
    off[base + i] = acc;
    cur[base + i] = acc;
    dinv[base + i] = rsqrtf((float)dg);
    acc += dg;
  }
  if (t == 255) off[N_NODES] = acc;  // == NEDGE
}

// ---- CSR fill ----
__global__ void fill_csr_kernel(const int* __restrict__ tgt, int* __restrict__ cur,
                                int* __restrict__ srcs) {
  int e = blockIdx.x * 256 + threadIdx.x;
  if (e >= NEDGE) return;
  int j = e / 5, q = e - j * 5;
  int target = (q < KNN) ? tgt[j * KNN + q] : j;
  int pos = atomicAdd(&cur[target], 1);
  srcs[pos] = j;
}

// ---- combined cvt: z<4 = fm batch transpose; z==4 = both weight transposes ----
__global__ void cvt_all_kernel(const float* __restrict__ fm, unsigned short* __restrict__ px0,
                               const float* __restrict__ W1, unsigned short* __restrict__ W1t,
                               const float* __restrict__ W2, unsigned short* __restrict__ W2t) {
  __shared__ float tile[32][33];
  int z = blockIdx.z;
  const float* in; unsigned short* out; int Rin, Cin, c0, r0;
  if (z < NB) {
    in = fm + (size_t)z * 256 * 4096; out = px0 + (size_t)z * 4096 * 256;
    Rin = 256; Cin = 4096;
    c0 = blockIdx.x * 32; r0 = blockIdx.y * 32;
  } else {
    int id = blockIdx.y * 128 + blockIdx.x;
    if (id < 128)      { in = W1; out = W1t; Rin = 256; Cin = 512; c0 = (id & 15) * 32; r0 = (id >> 4) * 32; }
    else if (id < 256) { id -= 128; in = W2; out = W2t; Rin = 512; Cin = 256; c0 = (id & 7) * 32; r0 = (id >> 3) * 32; }
    else return;
  }
  int tx = threadIdx.x & 31, ty = threadIdx.x >> 5;
  const float* ip = in + (size_t)r0 * Cin + c0;
#pragma unroll
  for (int i = 0; i < 32; i += 8) tile[ty + i][tx] = ip[(size_t)(ty + i) * Cin + tx];
  __syncthreads();
  unsigned short* op = out + (size_t)c0 * Rin + r0;
#pragma unroll
  for (int i = 0; i < 32; i += 8) op[(size_t)(ty + i) * Rin + tx] = f2bf(tile[tx][ty + i]);
}

// ---- propagate C=256 (bf16 -> bf16), 2 nodes/wave (16B/lane) ----
__global__ void prop_kernel(const unsigned short* __restrict__ in,
                            unsigned short* __restrict__ out,
                            const int* __restrict__ off, const int* __restrict__ srcs,
                            const float* __restrict__ dinv) {
  int i = blockIdx.x * 8 + (threadIdx.x >> 5);
  int l = threadIdx.x & 31;
  int e0 = off[i], e1 = off[i + 1];
  float a[8] = {};
  for (int e = e0; e < e1; ++e) {
    int j = srcs[e];
    float dj = dinv[j];
    u16x8 u = *(const u16x8*)(in + (size_t)j * 256 + l * 8);
#pragma unroll
    for (int k = 0; k < 8; ++k) a[k] = fmaf(dj, bf2f(u[k]), a[k]);
  }
  float di = dinv[i];
  u16x8 o;
#pragma unroll
  for (int k = 0; k < 8; ++k) o[k] = f2bf(a[k] * di);
  *(u16x8*)(out + (size_t)i * 256 + l * 8) = o;
}

// ---- propagate C=512 (bf16 -> bf16), 1 node/wave (16B/lane exactly) ----
__global__ void prop512_kernel(const unsigned short* __restrict__ in,
                               unsigned short* __restrict__ out,
                               const int* __restrict__ off, const int* __restrict__ srcs,
                               const float* __restrict__ dinv) {
  int i = blockIdx.x * 4 + (threadIdx.x >> 6);
  int l = threadIdx.x & 63;
  int e0 = off[i], e1 = off[i + 1];
  float a[8] = {};
  for (int e = e0; e < e1; ++e) {
    int j = srcs[e];
    float dj = dinv[j];
    u16x8 u = *(const u16x8*)(in + (size_t)j * 512 + l * 8);
#pragma unroll
    for (int k = 0; k < 8; ++k) a[k] = fmaf(dj, bf2f(u[k]), a[k]);
  }
  float di = dinv[i];
  u16x8 o;
#pragma unroll
  for (int k = 0; k < 8; ++k) o[k] = f2bf(a[k] * di);
  *(u16x8*)(out + (size_t)i * 512 + l * 8) = o;
}

// ---- bf16 MFMA GEMM (layer1): C[M,N] = A[M,K]@Bt[N,K]^T +bias,relu -> bf16 ----
__global__ __launch_bounds__(256)
void gemm1_kernel(const unsigned short* __restrict__ A,
                  const unsigned short* __restrict__ Bt,
                  unsigned short* __restrict__ C, const float* __restrict__ bias,
                  int M, int N, int K) {
  __shared__ char lds[24576];   // A: [64][128B] @0 ; B: [128][128B] @8192
  const int tid = threadIdx.x;
  const int l = tid & 63, w = tid >> 6;
  const int bm = blockIdx.x * 64, bn = blockIdx.y * 128;
  f32x4 acc[4][2] = {};

  for (int k0 = 0; k0 < K; k0 += 64) {
    __syncthreads();
#pragma unroll
    for (int q = 0; q < 2; ++q) {
      int o = q * 4096 + tid * 16;
      int r = o >> 7;
      int gc = ((o >> 4) & 7) ^ (r & 7);
      const char* srcA = (const char*)A + ((size_t)(bm + r) * K + k0) * 2 + gc * 16;
      __builtin_amdgcn_global_load_lds(
          (const __attribute__((address_space(1))) void*)srcA,
          (__attribute__((address_space(3))) void*)(lds + o), 16, 0, 0);
    }
#pragma unroll
    for (int q = 0; q < 4; ++q) {
      int o = q * 4096 + tid * 16;
      int r = o >> 7;
      int gc = ((o >> 4) & 7) ^ (r & 7);
      const char* srcB = (const char*)Bt + ((size_t)(bn + r) * K + k0) * 2 + gc * 16;
      __builtin_amdgcn_global_load_lds(
          (const __attribute__((address_space(1))) void*)srcB,
          (__attribute__((address_space(3))) void*)(lds + 8192 + o), 16, 0, 0);
    }
    __syncthreads();

#pragma unroll
    for (int kk = 0; kk < 64; kk += 32) {
      bf16x8 af[4], bf[2];
      int gc = (kk >> 3) + (l >> 4);
#pragma unroll
      for (int mi = 0; mi < 4; ++mi) {
        int r = mi * 16 + (l & 15);
        af[mi] = *(const bf16x8*)(lds + r * 128 + ((gc ^ (r & 7)) << 4));
      }
#pragma unroll
      for (int ni = 0; ni < 2; ++ni) {
        int r = w * 32 + ni * 16 + (l & 15);
        bf[ni] = *(const bf16x8*)(lds + 8192 + r * 128 + ((gc ^ (r & 7)) << 4));
      }
#pragma unroll
      for (int mi = 0; mi < 4; ++mi)
#pragma unroll
        for (int ni = 0; ni < 2; ++ni)
          acc[mi][ni] = __builtin_amdgcn_mfma_f32_16x16x32_bf16(af[mi], bf[ni],
                                                                acc[mi][ni], 0, 0, 0);
    }
  }

#pragma unroll
  for (int mi = 0; mi < 4; ++mi) {
#pragma unroll
    for (int ni = 0; ni < 2; ++ni) {
      int row0 = bm + mi * 16 + ((l >> 4) << 2);
      int col = bn + w * 32 + ni * 16 + (l & 15);
      float bv = bias[col];
      f32x4 v = acc[mi][ni];
#pragma unroll
      for (int r = 0; r < 4; ++r)
        C[(size_t)(row0 + r) * N + col] = f2bf(fmaxf(v[r] + bv, 0.f));
    }
  }
}

// ---- gemm2t: C = A[M,512]@Bt[256,512]^T + bias, relu, TRANSPOSED store ----
// Epilogue stages the 64x128 block through padded LDS [128][65] f32 and writes
// out[b][c][n] rows coalesced (256B). Eliminates t2/xout/transpose.
__global__ __launch_bounds__(256)
void gemm2t_kernel(const unsigned short* __restrict__ A,
                   const unsigned short* __restrict__ Bt,
                   float* __restrict__ out,         // [4][256][4096]
                   const float* __restrict__ bias,  // [256]
                   int K) {
  __shared__ __align__(16) char lds[33280];   // main: A 8KB + B 16KB; epi: [128][65] f32
  const int tid = threadIdx.x;
  const int l = tid & 63, w = tid >> 6;
  const int bm = blockIdx.x * 64, bn = blockIdx.y * 128;
  f32x4 acc[4][2] = {};

  for (int k0 = 0; k0 < K; k0 += 64) {
    __syncthreads();
#pragma unroll
    for (int q = 0; q < 2; ++q) {
      int o = q * 4096 + tid * 16;
      int r = o >> 7;
      int gc = ((o >> 4) & 7) ^ (r & 7);
      const char* srcA = (const char*)A + ((size_t)(bm + r) * K + k0) * 2 + gc * 16;
      __builtin_amdgcn_global_load_lds(
          (const __attribute__((address_space(1))) void*)srcA,
          (__attribute__((address_space(3))) void*)(lds + o), 16, 0, 0);
    }
#pragma unroll
    for (int q = 0; q < 4; ++q) {
      int o = q * 4096 + tid * 16;
      int r = o >> 7;
      int gc = ((o >> 4) & 7) ^ (r & 7);
      const char* srcB = (const char*)Bt + ((size_t)(bn + r) * K + k0) * 2 + gc * 16;
      __builtin_amdgcn_global_load_lds(
          (const __attribute__((address_space(1))) void*)srcB,
          (__attribute__((address_space(3))) void*)(lds + 8192 + o), 16, 0, 0);
    }
    __syncthreads();

#pragma unroll
    for (int kk = 0; kk < 64; kk += 32) {
      bf16x8 af[4], bf[2];
      int gc = (kk >> 3) + (l >> 4);
#pragma unroll
      for (int mi = 0; mi < 4; ++mi) {
        int r = mi * 16 + (l & 15);
        af[mi] = *(const bf16x8*)(lds + r * 128 + ((gc ^ (r & 7)) << 4));
      }
#pragma unroll
      for (int ni = 0; ni < 2; ++ni) {
        int r = w * 32 + ni * 16 + (l & 15);
        bf[ni] = *(const bf16x8*)(lds + 8192 + r * 128 + ((gc ^ (r & 7)) << 4));
      }
#pragma unroll
      for (int mi = 0; mi < 4; ++mi)
#pragma unroll
        for (int ni = 0; ni < 2; ++ni)
          acc[mi][ni] = __builtin_amdgcn_mfma_f32_16x16x32_bf16(af[mi], bf[ni],
                                                                acc[mi][ni], 0, 0, 0);
    }
  }

  __syncthreads();   // all LDS reads done before retile
  float* tile = (float*)lds;   // [128][65]
#pragma unroll
  for (int mi = 0; mi < 4; ++mi) {
#pragma unroll
    for (int ni = 0; ni < 2; ++ni) {
      int nloc = mi * 16 + ((l >> 4) << 2);
      int cloc = w * 32 + ni * 16 + (l & 15);
      float bv = bias[bn + cloc];
      f32x4 v = acc[mi][ni];
#pragma unroll
      for (int r = 0; r < 4; ++r)
        tile[cloc * 65 + nloc + r] = fmaxf(v[r] + bv, 0.f);
    }
  }
  __syncthreads();
  // write out[b][bn+c][n0l .. n0l+63], two 128B segments per row
  int c = tid >> 1, seg = (tid & 1) * 32;
  int b = bm >> 12, n0l = bm & (NPB - 1);
  float* op = out + ((size_t)b * 256 + bn + c) * 4096 + n0l + seg;
#pragma unroll
  for (int q = 0; q < 8; ++q) {
    float4 vv;
    vv.x = tile[c * 65 + seg + q * 4 + 0];
    vv.y = tile[c * 65 + seg + q * 4 + 1];
    vv.z = tile[c * 65 + seg + q * 4 + 2];
    vv.w = tile[c * 65 + seg + q * 4 + 3];
    *(float4*)(op + q * 4) = vv;
  }
}

// ---- launch ----
extern "C" void kernel_launch(void* const* d_in, const int* in_sizes, int n_in,
                              void* d_out, int out_size, void* d_ws, size_t ws_size,
                              hipStream_t stream) {
  const float* dm = (const float*)d_in[0];
  const float* fm = (const float*)d_in[1];
  const float* W1 = (const float*)d_in[2];
  const float* b1 = (const float*)d_in[3];
  const float* W2 = (const float*)d_in[4];
  const float* b2 = (const float*)d_in[5];
  float* out = (float*)d_out;

  char* ws = (char*)d_ws;
  int*                tgt   = (int*)(ws + 0x000000);               // 256KB
  int*                deg   = (int*)(ws + 0x040000);               // 64KB
  float*              dinv  = (float*)(ws + 0x050000);             // 64KB
  int*                off   = (int*)(ws + 0x060000);               // 64KB+4
  int*                cur   = (int*)(ws + 0x080000);               // 64KB+4
  int*                srcs  = (int*)(ws + 0x0A0000);               // 320KB
  unsigned long long* skeys = (unsigned long long*)(ws + 0x100000);// 128KB
  int*                bstart= (int*)(ws + 0x140000);               // 64KB+4
  unsigned long long* tmpkeys = (unsigned long long*)(ws + 0x170000); // 128KB
  unsigned short*     W1t   = (unsigned short*)(ws + 0x190000);    // 256KB
  unsigned short*     W2t   = (unsigned short*)(ws + 0x1D0000);    // 256KB
  unsigned short*     px0   = (unsigned short*)(ws + 0x0400000);   // 8MB
  unsigned short*     px    = (unsigned short*)(ws + 0x0C00000);   // 8MB
  unsigned short*     h1    = (unsigned short*)(ws + 0x1400000);   // 16MB
  unsigned short*     ph    = (unsigned short*)(ws + 0x2400000);   // 16MB
  (void)ws_size; (void)in_sizes; (void)n_in; (void)out_size;

  // ---- graph build: 5 kernels ----
  bucket_kernel<<<NB, 1024, 0, stream>>>(dm, tmpkeys, bstart, deg);
  bfinal_kernel<<<64, 256, 0, stream>>>(tmpkeys, bstart, skeys);
  knn_select_kernel<<<64, 256, 0, stream>>>(skeys, tgt, deg);
  scan_kernel<<<1, 256, 0, stream>>>(deg, dinv, off, cur);
  fill_csr_kernel<<<NEDGE / 256, 256, 0, stream>>>(tgt, cur, srcs);

  // ---- all input conversions in one launch ----
  cvt_all_kernel<<<dim3(128, 8, NB + 1), 256, 0, stream>>>(fm, px0, W1, W1t, W2, W2t);

  // layer 1: propagate (256) then GEMM relu(.@W1+b1) -> bf16
  prop_kernel<<<N_NODES / 8, 256, 0, stream>>>(px0, px, off, srcs, dinv);
  gemm1_kernel<<<dim3(256, 4), 256, 0, stream>>>(px, W1t, h1, b1, 16384, 512, 256);

  // layer 2 (reordered): propagate h1 (512) then GEMM + bias + relu with
  // transposed store directly into out[B][256][4096]
  prop512_kernel<<<N_NODES / 4, 256, 0, stream>>>(h1, ph, off, srcs, dinv);
  gemm2t_kernel<<<dim3(256, 2), 256, 0, stream>>>(ph, W2t, out, b2, 512);
}

// Round 15
// 97.896 us; speedup vs baseline: 1.0881x; 1.0881x over previous
//
#include <hip/hip_runtime.h>
#include <hip/hip_bf16.h>
#include <stdint.h>

#define N_NODES 16384   // B*H*W
#define NPB     4096    // nodes per batch
#define NB      4
#define KNN     4
#define NEDGE   (N_NODES * 5)
#define WIN     12      // sorted-order window radius for exact 1-D kNN
#define NBUK    4096

typedef short bf16x8 __attribute__((ext_vector_type(8)));
typedef float f32x4 __attribute__((ext_vector_type(4)));
typedef unsigned short u16x8 __attribute__((ext_vector_type(8)));

__device__ __forceinline__ unsigned short f2bf(float f) {
  unsigned u = __float_as_uint(f);
  unsigned r = (u + 0x7fff + ((u >> 16) & 1)) >> 16;   // RNE
  return (unsigned short)r;
}
__device__ __forceinline__ float bf2f(unsigned short u) {
  return __uint_as_float(((unsigned)u) << 16);
}

// ---- fused bucket stage: hist + scan + scatter + in-LDS bucket sort ----
// One block per batch (4 x 1024). LDS = 16+16+32 = 64KB exactly; the scan
// scratch (part1/part2) aliases the key array (used strictly before it).
// Emits fully sorted per-batch skeys (replaces old bfinal kernel).
__global__ __launch_bounds__(1024)
void bucket_kernel(const float* __restrict__ dm,
                   unsigned long long* __restrict__ skeys_g,
                   int* __restrict__ deg) {
  __shared__ int sHist[4096];                 // counts -> bucket starts (in place)
  __shared__ int sCur[4096];                  // running cursor for scatter
  __shared__ unsigned long long sKeys[4096];  // sorted keys; aliases part1/part2
  int* part1 = (int*)sKeys;                   // [1024]
  int* part2 = (int*)(sKeys + 512);           // [64]
  const int t = threadIdx.x, b = blockIdx.x;
  const float* d = dm + b * NPB;

  unsigned long long kv[4]; int bk[4];
#pragma unroll
  for (int r = 0; r < 4; ++r) {
    int i = t + r * 1024;
    sHist[i] = 0;
    deg[b * NPB + i] = 1;
  }
  __syncthreads();
#pragma unroll
  for (int r = 0; r < 4; ++r) {
    int i = t + r * 1024;
    float v = d[i];
    kv[r] = (((unsigned long long)__float_as_uint(v)) << 32) | (unsigned)i;
    int k = (int)(v * (float)NBUK); if (k > NBUK - 1) k = NBUK - 1;
    bk[r] = k;
    atomicAdd(&sHist[k], 1);
  }
  __syncthreads();
  // scan: save own counts, hierarchical prefix via part1/part2 (in sKeys alias)
  int c0 = sHist[4 * t + 0], c1 = sHist[4 * t + 1];
  int c2 = sHist[4 * t + 2], c3 = sHist[4 * t + 3];
  part1[t] = c0 + c1 + c2 + c3;
  __syncthreads();
  if (t < 64) {
    int s = 0;
#pragma unroll
    for (int k = 0; k < 16; ++k) s += part1[16 * t + k];
    part2[t] = s;
  }
  __syncthreads();
  if (t == 0) {
    int a = 0;
    for (int u = 0; u < 64; ++u) { int v = part2[u]; part2[u] = a; a += v; }
  }
  __syncthreads();
  int base = part2[t >> 4];
  for (int k = (t >> 4) * 16; k < t; ++k) base += part1[k];
  sHist[4 * t + 0] = base; sCur[4 * t + 0] = base; base += c0;
  sHist[4 * t + 1] = base; sCur[4 * t + 1] = base; base += c1;
  sHist[4 * t + 2] = base; sCur[4 * t + 2] = base; base += c2;
  sHist[4 * t + 3] = base; sCur[4 * t + 3] = base;
  __syncthreads();   // part1/part2 reads done -> sKeys may now be written
  // scatter into LDS key slots
#pragma unroll
  for (int r = 0; r < 4; ++r) {
    int slot = atomicAdd(&sCur[bk[r]], 1);
    sKeys[slot] = kv[r];
  }
  __syncthreads();
  // per-bucket insertion sort (avg 1 elem/bucket) -> exact (value,idx) order
#pragma unroll
  for (int r = 0; r < 4; ++r) {
    int g = t + r * 1024;
    int s0 = sHist[g];
    int s1 = (g == NPB - 1) ? NPB : sHist[g + 1];
    for (int i = s0 + 1; i < s1; ++i) {
      unsigned long long x = sKeys[i];
      int j = i - 1;
      while (j >= s0 && sKeys[j] > x) { sKeys[j + 1] = sKeys[j]; --j; }
      sKeys[j + 1] = x;
    }
  }
  __syncthreads();
  // coalesced write of the sorted batch
#pragma unroll
  for (int r = 0; r < 4; ++r) {
    int i = t + r * 1024;
    skeys_g[b * NPB + i] = sKeys[i];
  }
}

// ---- kNN select driven by sorted position ----
__global__ void knn_select_kernel(const unsigned long long* __restrict__ skeys,
                                  int* __restrict__ tgt, int* __restrict__ deg) {
  int p = blockIdx.x * 256 + threadIdx.x;   // global sorted slot
  if (p >= N_NODES) return;
  int b = p >> 12, pl = p & (NPB - 1);
  const unsigned long long* sk = skeys + b * NPB;
  unsigned long long kp = sk[pl];
  float di = __uint_as_float((unsigned)(kp >> 32));
  int node = b * NPB + (int)(kp & 0xffffffffull);
  int lo = pl - WIN; if (lo < 0) lo = 0;
  int hi = pl + WIN; if (hi > NPB - 1) hi = NPB - 1;
  unsigned long long k0 = ~0ull, k1 = ~0ull, k2 = ~0ull, k3 = ~0ull, k4 = ~0ull;
  for (int q = lo; q <= hi; ++q) {
    unsigned long long key = sk[q];
    float v = __uint_as_float((unsigned)(key >> 32));
    float dist = fabsf(di - v);
    unsigned long long dk = (((unsigned long long)__float_as_uint(dist)) << 32) |
                            (key & 0xffffffffull);
    if (dk < k4) {
      if (dk < k0)      { k4 = k3; k3 = k2; k2 = k1; k1 = k0; k0 = dk; }
      else if (dk < k1) { k4 = k3; k3 = k2; k2 = k1; k1 = dk; }
      else if (dk < k2) { k4 = k3; k3 = k2; k2 = dk; }
      else if (dk < k3) { k4 = k3; k3 = dk; }
      else              { k4 = dk; }
    }
  }
  int base = b * NPB;
  int t0 = base + (int)(k1 & 0xffffffffull);
  int t1 = base + (int)(k2 & 0xffffffffull);
  int t2 = base + (int)(k3 & 0xffffffffull);
  int t3 = base + (int)(k4 & 0xffffffffull);
  tgt[node * KNN + 0] = t0; atomicAdd(&deg[t0], 1);
  tgt[node * KNN + 1] = t1; atomicAdd(&deg[t1], 1);
  tgt[node * KNN + 2] = t2; atomicAdd(&deg[t2], 1);
  tgt[node * KNN + 3] = t3; atomicAdd(&deg[t3], 1);
}

// ---- dinv + exclusive scan of deg (single block) ----
__global__ void scan_kernel(const int* __restrict__ deg, float* __restrict__ dinv,
                            int* __restrict__ off, int* __restrict__ cur) {
  __shared__ int part[256];
  int t = threadIdx.x;
  int base = t * 64;
  int s = 0;
  for (int i = 0; i < 64; ++i) s += deg[base + i];
  part[t] = s;
  __syncthreads();
  if (t == 0) {
    int acc = 0;
    for (int i = 0; i < 256; ++i) { int v = part[i]; part[i] = acc; acc += v; }
  }
  __syncthreads();
  int acc = part[t];
  for (int i = 0; i < 64; ++i) {
    int dg = deg[base + i];
    off[base + i] = acc;
    cur[base + i] = acc;
    dinv[base + i] = rsqrtf((float)dg);
    acc += dg;
  }
  if (t == 255) off[N_NODES] = acc;  // == NEDGE
}

// ---- CSR fill ----
__global__ void fill_csr_kernel(const int* __restrict__ tgt, int* __restrict__ cur,
                                int* __restrict__ srcs) {
  int e = blockIdx.x * 256 + threadIdx.x;
  if (e >= NEDGE) return;
  int j = e / 5, q = e - j * 5;
  int target = (q < KNN) ? tgt[j * KNN + q] : j;
  int pos = atomicAdd(&cur[target], 1);
  srcs[pos] = j;
}

// ---- combined cvt with 128B bf16 stores: 64-row x 32-col input tiles ----
// z<4: fm batch transpose [256][4096] -> [4096][256] bf16; z==4,y==0: weights.
__global__ void cvt_all_kernel(const float* __restrict__ fm, unsigned short* __restrict__ px0,
                               const float* __restrict__ W1, unsigned short* __restrict__ W1t,
                               const float* __restrict__ W2, unsigned short* __restrict__ W2t) {
  __shared__ float tile[64][33];
  int z = blockIdx.z;
  const float* in; unsigned short* out; int Rin, Cin, r0, c0;
  if (z < NB) {
    in = fm + (size_t)z * 256 * 4096; out = px0 + (size_t)z * 4096 * 256;
    Rin = 256; Cin = 4096;
    c0 = blockIdx.x * 32; r0 = blockIdx.y * 64;
  } else {
    int id = blockIdx.y * 128 + blockIdx.x;
    if (id < 64)       { in = W1; out = W1t; Rin = 256; Cin = 512; c0 = (id & 15) * 32; r0 = (id >> 4) * 64; }
    else if (id < 128) { id -= 64; in = W2; out = W2t; Rin = 512; Cin = 256; c0 = (id & 7) * 32; r0 = (id >> 3) * 64; }
    else return;
  }
  int tx = threadIdx.x & 31, ty = threadIdx.x >> 5;   // ty 0..7
  const float* ip = in + (size_t)(r0 + ty) * Cin + c0 + tx;
#pragma unroll
  for (int i = 0; i < 8; ++i) tile[ty + 8 * i][tx] = ip[(size_t)(8 * i) * Cin];
  __syncthreads();
  int orow = threadIdx.x >> 3;        // 0..31 (input col)
  int oseg = (threadIdx.x & 7) * 8;   // 0..56 (input row offset)
  unsigned short* op = out + (size_t)(c0 + orow) * Rin + r0 + oseg;
  u16x8 o;
#pragma unroll
  for (int k = 0; k < 8; ++k) o[k] = f2bf(tile[oseg + k][orow]);
  *(u16x8*)op = o;
}

// ---- fp32 batched transpose: [B][Rin][Cin] -> [B][Cin][Rin] ----
__global__ void transpose_kernel(const float* __restrict__ in, float* __restrict__ out,
                                 int Rin, int Cin) {
  __shared__ float tile[32][33];
  int c0 = blockIdx.x * 32, r0 = blockIdx.y * 32, b = blockIdx.z;
  int tx = threadIdx.x & 31, ty = threadIdx.x >> 5;
  const float* ip = in + ((size_t)b * Rin + r0) * Cin + c0;
#pragma unroll
  for (int i = 0; i < 32; i += 8) tile[ty + i][tx] = ip[(size_t)(ty + i) * Cin + tx];
  __syncthreads();
  float* op = out + ((size_t)b * Cin + c0) * Rin + r0;
#pragma unroll
  for (int i = 0; i < 32; i += 8) op[(size_t)(ty + i) * Rin + tx] = tile[tx][ty + i];
}

// ---- propagate C=256 (bf16 -> bf16), 2 nodes/wave (16B/lane) ----
__global__ void prop_kernel(const unsigned short* __restrict__ in,
                            unsigned short* __restrict__ out,
                            const int* __restrict__ off, const int* __restrict__ srcs,
                            const float* __restrict__ dinv) {
  int i = blockIdx.x * 8 + (threadIdx.x >> 5);
  int l = threadIdx.x & 31;
  int e0 = off[i], e1 = off[i + 1];
  float a[8] = {};
  for (int e = e0; e < e1; ++e) {
    int j = srcs[e];
    float dj = dinv[j];
    u16x8 u = *(const u16x8*)(in + (size_t)j * 256 + l * 8);
#pragma unroll
    for (int k = 0; k < 8; ++k) a[k] = fmaf(dj, bf2f(u[k]), a[k]);
  }
  float di = dinv[i];
  u16x8 o;
#pragma unroll
  for (int k = 0; k < 8; ++k) o[k] = f2bf(a[k] * di);
  *(u16x8*)(out + (size_t)i * 256 + l * 8) = o;
}

// ---- propagate + bias + relu (bf16 -> f32 node-major), 2 nodes/wave ----
__global__ void prop2_kernel(const unsigned short* __restrict__ in,
                             float* __restrict__ out,
                             const int* __restrict__ off, const int* __restrict__ srcs,
                             const float* __restrict__ dinv, const float* __restrict__ bias) {
  int i = blockIdx.x * 8 + (threadIdx.x >> 5);
  int l = threadIdx.x & 31;
  int e0 = off[i], e1 = off[i + 1];
  float a[8] = {};
  for (int e = e0; e < e1; ++e) {
    int j = srcs[e];
    float dj = dinv[j];
    u16x8 u = *(const u16x8*)(in + (size_t)j * 256 + l * 8);
#pragma unroll
    for (int k = 0; k < 8; ++k) a[k] = fmaf(dj, bf2f(u[k]), a[k]);
  }
  float di = dinv[i];
  float4 o0, o1;
  o0.x = fmaxf(a[0] * di + bias[l * 8 + 0], 0.f);
  o0.y = fmaxf(a[1] * di + bias[l * 8 + 1], 0.f);
  o0.z = fmaxf(a[2] * di + bias[l * 8 + 2], 0.f);
  o0.w = fmaxf(a[3] * di + bias[l * 8 + 3], 0.f);
  o1.x = fmaxf(a[4] * di + bias[l * 8 + 4], 0.f);
  o1.y = fmaxf(a[5] * di + bias[l * 8 + 5], 0.f);
  o1.z = fmaxf(a[6] * di + bias[l * 8 + 6], 0.f);
  o1.w = fmaxf(a[7] * di + bias[l * 8 + 7], 0.f);
  *(float4*)(out + (size_t)i * 256 + l * 8) = o0;
  *(float4*)(out + (size_t)i * 256 + l * 8 + 4) = o1;
}

// ---- bf16 MFMA GEMM: C[M,N] = A[M,K] @ Bt[N,K]^T (+bias, relu), 64x128 tile ----
template <bool BIAS_RELU, bool OUT_BF16>
__global__ __launch_bounds__(256)
void gemm_bf16_kernel(const unsigned short* __restrict__ A,
                      const unsigned short* __restrict__ Bt,
                      void* __restrict__ C, const float* __restrict__ bias,
                      int M, int N, int K) {
  __shared__ char lds[24576];   // A: [64][128B] @0 ; B: [128][128B] @8192
  const int tid = threadIdx.x;
  const int l = tid & 63, w = tid >> 6;
  const int bm = blockIdx.x * 64, bn = blockIdx.y * 128;
  f32x4 acc[4][2] = {};

  for (int k0 = 0; k0 < K; k0 += 64) {
    __syncthreads();
#pragma unroll
    for (int q = 0; q < 2; ++q) {          // A tile: 8KB
      int o = q * 4096 + tid * 16;
      int r = o >> 7;
      int gc = ((o >> 4) & 7) ^ (r & 7);
      const char* srcA = (const char*)A + ((size_t)(bm + r) * K + k0) * 2 + gc * 16;
      __builtin_amdgcn_global_load_lds(
          (const __attribute__((address_space(1))) void*)srcA,
          (__attribute__((address_space(3))) void*)(lds + o), 16, 0, 0);
    }
#pragma unroll
    for (int q = 0; q < 4; ++q) {          // B tile: 16KB
      int o = q * 4096 + tid * 16;
      int r = o >> 7;
      int gc = ((o >> 4) & 7) ^ (r & 7);
      const char* srcB = (const char*)Bt + ((size_t)(bn + r) * K + k0) * 2 + gc * 16;
      __builtin_amdgcn_global_load_lds(
          (const __attribute__((address_space(1))) void*)srcB,
          (__attribute__((address_space(3))) void*)(lds + 8192 + o), 16, 0, 0);
    }
    __syncthreads();

#pragma unroll
    for (int kk = 0; kk < 64; kk += 32) {
      bf16x8 af[4], bf[2];
      int gc = (kk >> 3) + (l >> 4);
#pragma unroll
      for (int mi = 0; mi < 4; ++mi) {
        int r = mi * 16 + (l & 15);
        af[mi] = *(const bf16x8*)(lds + r * 128 + ((gc ^ (r & 7)) << 4));
      }
#pragma unroll
      for (int ni = 0; ni < 2; ++ni) {
        int r = w * 32 + ni * 16 + (l & 15);
        bf[ni] = *(const bf16x8*)(lds + 8192 + r * 128 + ((gc ^ (r & 7)) << 4));
      }
#pragma unroll
      for (int mi = 0; mi < 4; ++mi)
#pragma unroll
        for (int ni = 0; ni < 2; ++ni)
          acc[mi][ni] = __builtin_amdgcn_mfma_f32_16x16x32_bf16(af[mi], bf[ni],
                                                                acc[mi][ni], 0, 0, 0);
    }
  }

#pragma unroll
  for (int mi = 0; mi < 4; ++mi) {
#pragma unroll
    for (int ni = 0; ni < 2; ++ni) {
      int row0 = bm + mi * 16 + ((l >> 4) << 2);
      int col = bn + w * 32 + ni * 16 + (l & 15);
      float bv = BIAS_RELU ? bias[col] : 0.f;
      f32x4 v = acc[mi][ni];
#pragma unroll
      for (int r = 0; r < 4; ++r) {
        float val = v[r];
        if (BIAS_RELU) val = fmaxf(val + bv, 0.f);
        if (OUT_BF16)
          ((unsigned short*)C)[(size_t)(row0 + r) * N + col] = f2bf(val);
        else
          ((float*)C)[(size_t)(row0 + r) * N + col] = val;
      }
    }
  }
}

// ---- launch ----
extern "C" void kernel_launch(void* const* d_in, const int* in_sizes, int n_in,
                              void* d_out, int out_size, void* d_ws, size_t ws_size,
                              hipStream_t stream) {
  const float* dm = (const float*)d_in[0];
  const float* fm = (const float*)d_in[1];
  const float* W1 = (const float*)d_in[2];
  const float* b1 = (const float*)d_in[3];
  const float* W2 = (const float*)d_in[4];
  const float* b2 = (const float*)d_in[5];
  float* out = (float*)d_out;

  char* ws = (char*)d_ws;
  int*                tgt   = (int*)(ws + 0x000000);               // 256KB
  int*                deg   = (int*)(ws + 0x040000);               // 64KB
  float*              dinv  = (float*)(ws + 0x050000);             // 64KB
  int*                off   = (int*)(ws + 0x060000);               // 64KB+4
  int*                cur   = (int*)(ws + 0x080000);               // 64KB+4
  int*                srcs  = (int*)(ws + 0x0A0000);               // 320KB
  unsigned long long* skeys = (unsigned long long*)(ws + 0x100000);// 128KB
  unsigned short*     W1t   = (unsigned short*)(ws + 0x190000);    // 256KB
  unsigned short*     W2t   = (unsigned short*)(ws + 0x1D0000);    // 256KB
  unsigned short*     px0   = (unsigned short*)(ws + 0x0400000);   // 8MB
  unsigned short*     px    = (unsigned short*)(ws + 0x0C00000);   // 8MB
  unsigned short*     h1    = (unsigned short*)(ws + 0x1400000);   // 16MB
  unsigned short*     t2    = (unsigned short*)(ws + 0x2400000);   // 8MB
  float*              xout  = (float*)(ws + 0x2C00000);            // 16MB
  (void)ws_size; (void)in_sizes; (void)n_in; (void)out_size;

  // ---- graph build: 4 kernels (bucket now emits sorted skeys directly) ----
  bucket_kernel<<<NB, 1024, 0, stream>>>(dm, skeys, deg);
  knn_select_kernel<<<64, 256, 0, stream>>>(skeys, tgt, deg);
  scan_kernel<<<1, 256, 0, stream>>>(deg, dinv, off, cur);
  fill_csr_kernel<<<NEDGE / 256, 256, 0, stream>>>(tgt, cur, srcs);

  // ---- all input conversions in one launch (128B-store tiles) ----
  cvt_all_kernel<<<dim3(128, 4, NB + 1), 256, 0, stream>>>(fm, px0, W1, W1t, W2, W2t);

  // layer 1: propagate (256) then GEMM relu(.@W1+b1) -> bf16
  prop_kernel<<<N_NODES / 8, 256, 0, stream>>>(px0, px, off, srcs, dinv);
  gemm_bf16_kernel<true, true><<<dim3(256, 4), 256, 0, stream>>>(
      px, W1t, h1, b1, 16384, 512, 256);

  // layer 2: GEMM h1@W2 -> bf16, then propagate+bias+relu (f32 node-major)
  gemm_bf16_kernel<false, true><<<dim3(256, 2), 256, 0, stream>>>(
      h1, W2t, t2, nullptr, 16384, 256, 512);
  prop2_kernel<<<N_NODES / 8, 256, 0, stream>>>(t2, xout, off, srcs, dinv, b2);

  // node-major -> [B][256][4096]
  transpose_kernel<<<dim3(8, 128, NB), 256, 0, stream>>>(xout, out, 4096, 256);
}

// Round 16
// 95.588 us; speedup vs baseline: 1.1143x; 1.0241x over previous
//
#include <hip/hip_runtime.h>
#include <hip/hip_bf16.h>
#include <stdint.h>

#define N_NODES 16384   // B*H*W
#define NPB     4096    // nodes per batch
#define NB      4
#define KNN     4
#define NEDGE   (N_NODES * 5)
#define WIN     12      // sorted-order window radius for exact 1-D kNN
#define NBUK    4096

typedef short bf16x8 __attribute__((ext_vector_type(8)));
typedef float f32x4 __attribute__((ext_vector_type(4)));
typedef unsigned short u16x8 __attribute__((ext_vector_type(8)));

__device__ __forceinline__ unsigned short f2bf(float f) {
  unsigned u = __float_as_uint(f);
  unsigned r = (u + 0x7fff + ((u >> 16) & 1)) >> 16;   // RNE
  return (unsigned short)r;
}
__device__ __forceinline__ float bf2f(unsigned short u) {
  return __uint_as_float(((unsigned)u) << 16);
}

// ---- fused bucket stage: hist + scan + scatter + in-LDS bucket sort ----
// One block per batch (4 x 1024). Emits sorted per-batch skeys AND rank
// (node -> batch-local sorted position, for the permuted feature layout).
__global__ __launch_bounds__(1024)
void bucket_kernel(const float* __restrict__ dm,
                   unsigned long long* __restrict__ skeys_g,
                   int* __restrict__ rank_g,
                   int* __restrict__ deg) {
  __shared__ int sHist[4096];
  __shared__ int sCur[4096];
  __shared__ unsigned long long sKeys[4096];  // aliases part1/part2 (scan scratch)
  int* part1 = (int*)sKeys;                   // [1024]
  int* part2 = (int*)(sKeys + 512);           // [64]
  const int t = threadIdx.x, b = blockIdx.x;
  const float* d = dm + b * NPB;

  unsigned long long kv[4]; int bk[4];
#pragma unroll
  for (int r = 0; r < 4; ++r) {
    int i = t + r * 1024;
    sHist[i] = 0;
    deg[b * NPB + i] = 1;   // deg indexed by sorted position; self-loop
  }
  __syncthreads();
#pragma unroll
  for (int r = 0; r < 4; ++r) {
    int i = t + r * 1024;
    float v = d[i];
    kv[r] = (((unsigned long long)__float_as_uint(v)) << 32) | (unsigned)i;
    int k = (int)(v * (float)NBUK); if (k > NBUK - 1) k = NBUK - 1;
    bk[r] = k;
    atomicAdd(&sHist[k], 1);
  }
  __syncthreads();
  int c0 = sHist[4 * t + 0], c1 = sHist[4 * t + 1];
  int c2 = sHist[4 * t + 2], c3 = sHist[4 * t + 3];
  part1[t] = c0 + c1 + c2 + c3;
  __syncthreads();
  if (t < 64) {
    int s = 0;
#pragma unroll
    for (int k = 0; k < 16; ++k) s += part1[16 * t + k];
    part2[t] = s;
  }
  __syncthreads();
  if (t == 0) {
    int a = 0;
    for (int u = 0; u < 64; ++u) { int v = part2[u]; part2[u] = a; a += v; }
  }
  __syncthreads();
  int base = part2[t >> 4];
  for (int k = (t >> 4) * 16; k < t; ++k) base += part1[k];
  sHist[4 * t + 0] = base; sCur[4 * t + 0] = base; base += c0;
  sHist[4 * t + 1] = base; sCur[4 * t + 1] = base; base += c1;
  sHist[4 * t + 2] = base; sCur[4 * t + 2] = base; base += c2;
  sHist[4 * t + 3] = base; sCur[4 * t + 3] = base;
  __syncthreads();   // scan scratch dead -> sKeys writable
#pragma unroll
  for (int r = 0; r < 4; ++r) {
    int slot = atomicAdd(&sCur[bk[r]], 1);
    sKeys[slot] = kv[r];
  }
  __syncthreads();
#pragma unroll
  for (int r = 0; r < 4; ++r) {
    int g = t + r * 1024;
    int s0 = sHist[g];
    int s1 = (g == NPB - 1) ? NPB : sHist[g + 1];
    for (int i = s0 + 1; i < s1; ++i) {
      unsigned long long x = sKeys[i];
      int j = i - 1;
      while (j >= s0 && sKeys[j] > x) { sKeys[j + 1] = sKeys[j]; --j; }
      sKeys[j + 1] = x;
    }
  }
  __syncthreads();
#pragma unroll
  for (int r = 0; r < 4; ++r) {
    int i = t + r * 1024;
    unsigned long long k = sKeys[i];
    skeys_g[b * NPB + i] = k;
    rank_g[b * NPB + (int)(k & 0xffffffffull)] = i;   // batch-local position
  }
}

// ---- kNN select in SORTED-POSITION space ----
// dk = (dist<<24)|(idx<<12)|pos : order is (dist, idx) lexicographic (exact
// argsort semantics); pos rides along so targets come out as positions.
__global__ void knn_select_kernel(const unsigned long long* __restrict__ skeys,
                                  int* __restrict__ tgt, int* __restrict__ deg) {
  int p = blockIdx.x * 256 + threadIdx.x;   // global sorted slot
  if (p >= N_NODES) return;
  int b = p >> 12, pl = p & (NPB - 1);
  const unsigned long long* sk = skeys + b * NPB;
  unsigned long long kp = sk[pl];
  float di = __uint_as_float((unsigned)(kp >> 32));
  int lo = pl - WIN; if (lo < 0) lo = 0;
  int hi = pl + WIN; if (hi > NPB - 1) hi = NPB - 1;
  unsigned long long k0 = ~0ull, k1 = ~0ull, k2 = ~0ull, k3 = ~0ull, k4 = ~0ull;
  for (int q = lo; q <= hi; ++q) {
    unsigned long long key = sk[q];
    float v = __uint_as_float((unsigned)(key >> 32));
    float dist = fabsf(di - v);
    unsigned long long dk = (((unsigned long long)__float_as_uint(dist)) << 24) |
                            ((key & 0xfffull) << 12) | (unsigned)q;
    if (dk < k4) {
      if (dk < k0)      { k4 = k3; k3 = k2; k2 = k1; k1 = k0; k0 = dk; }
      else if (dk < k1) { k4 = k3; k3 = k2; k2 = k1; k1 = dk; }
      else if (dk < k2) { k4 = k3; k3 = k2; k2 = dk; }
      else if (dk < k3) { k4 = k3; k3 = dk; }
      else              { k4 = dk; }
    }
  }
  int base = b * NPB;
  int t0 = base + (int)(k1 & 0xfff);
  int t1 = base + (int)(k2 & 0xfff);
  int t2 = base + (int)(k3 & 0xfff);
  int t3 = base + (int)(k4 & 0xfff);
  tgt[p * KNN + 0] = t0; atomicAdd(&deg[t0], 1);
  tgt[p * KNN + 1] = t1; atomicAdd(&deg[t1], 1);
  tgt[p * KNN + 2] = t2; atomicAdd(&deg[t2], 1);
  tgt[p * KNN + 3] = t3; atomicAdd(&deg[t3], 1);
}

// ---- dinv + exclusive scan of deg (single block); position space ----
__global__ void scan_kernel(const int* __restrict__ deg, float* __restrict__ dinv,
                            int* __restrict__ off, int* __restrict__ cur) {
  __shared__ int part[256];
  int t = threadIdx.x;
  int base = t * 64;
  int s = 0;
  for (int i = 0; i < 64; ++i) s += deg[base + i];
  part[t] = s;
  __syncthreads();
  if (t == 0) {
    int acc = 0;
    for (int i = 0; i < 256; ++i) { int v = part[i]; part[i] = acc; acc += v; }
  }
  __syncthreads();
  int acc = part[t];
  for (int i = 0; i < 64; ++i) {
    int dg = deg[base + i];
    off[base + i] = acc;
    cur[base + i] = acc;
    dinv[base + i] = rsqrtf((float)dg);
    acc += dg;
  }
  if (t == 255) off[N_NODES] = acc;  // == NEDGE
}

// ---- CSR fill; sources are sorted positions ----
__global__ void fill_csr_kernel(const int* __restrict__ tgt, int* __restrict__ cur,
                                int* __restrict__ srcs) {
  int e = blockIdx.x * 256 + threadIdx.x;
  if (e >= NEDGE) return;
  int p = e / 5, q = e - p * 5;
  int target = (q < KNN) ? tgt[p * KNN + q] : p;   // q==4 -> self loop
  int pos = atomicAdd(&cur[target], 1);
  srcs[pos] = p;
}

// ---- combined cvt with 128B bf16 stores + PERMUTED node rows ----
// z<4: fm [256][4096] -> px0[rank(n)][256] bf16 (sorted-space layout);
// z==4: both weight transposes (unpermuted).
__global__ void cvt_all_kernel(const float* __restrict__ fm, unsigned short* __restrict__ px0,
                               const float* __restrict__ W1, unsigned short* __restrict__ W1t,
                               const float* __restrict__ W2, unsigned short* __restrict__ W2t,
                               const int* __restrict__ rank) {
  __shared__ float tile[64][33];
  int z = blockIdx.z;
  const float* in; unsigned short* outbase; int Rin, Cin, r0, c0;
  bool perm = false;
  if (z < NB) {
    in = fm + (size_t)z * 256 * 4096; outbase = px0 + (size_t)z * NPB * 256;
    Rin = 256; Cin = 4096; perm = true;
    c0 = blockIdx.x * 32; r0 = blockIdx.y * 64;
  } else {
    int id = blockIdx.y * 128 + blockIdx.x;
    if (id < 64)       { in = W1; outbase = W1t; Rin = 256; Cin = 512; c0 = (id & 15) * 32; r0 = (id >> 4) * 64; }
    else if (id < 128) { id -= 64; in = W2; outbase = W2t; Rin = 512; Cin = 256; c0 = (id & 7) * 32; r0 = (id >> 3) * 64; }
    else return;
  }
  int tx = threadIdx.x & 31, ty = threadIdx.x >> 5;   // ty 0..7
  const float* ip = in + (size_t)(r0 + ty) * Cin + c0 + tx;
#pragma unroll
  for (int i = 0; i < 8; ++i) tile[ty + 8 * i][tx] = ip[(size_t)(8 * i) * Cin];
  __syncthreads();
  int orow = threadIdx.x >> 3;        // 0..31 (input col / node)
  int oseg = (threadIdx.x & 7) * 8;   // 0..56 (input row offset)
  int outrow = c0 + orow;
  if (perm) outrow = rank[(size_t)z * NPB + outrow];
  unsigned short* op = outbase + (size_t)outrow * Rin + r0 + oseg;
  u16x8 o;
#pragma unroll
  for (int k = 0; k < 8; ++k) o[k] = f2bf(tile[oseg + k][orow]);
  *(u16x8*)op = o;
}

// ---- fp32 batched transpose: [B][Rin][Cin] -> [B][Cin][Rin] ----
__global__ void transpose_kernel(const float* __restrict__ in, float* __restrict__ out,
                                 int Rin, int Cin) {
  __shared__ float tile[32][33];
  int c0 = blockIdx.x * 32, r0 = blockIdx.y * 32, b = blockIdx.z;
  int tx = threadIdx.x & 31, ty = threadIdx.x >> 5;
  const float* ip = in + ((size_t)b * Rin + r0) * Cin + c0;
#pragma unroll
  for (int i = 0; i < 32; i += 8) tile[ty + i][tx] = ip[(size_t)(ty + i) * Cin + tx];
  __syncthreads();
  float* op = out + ((size_t)b * Cin + c0) * Rin + r0;
#pragma unroll
  for (int i = 0; i < 32; i += 8) op[(size_t)(ty + i) * Rin + tx] = tile[tx][ty + i];
}

// ---- propagate C=256 (bf16 -> bf16), 2 nodes/wave; WINDOW-LOCAL gathers ----
__global__ void prop_kernel(const unsigned short* __restrict__ in,
                            unsigned short* __restrict__ out,
                            const int* __restrict__ off, const int* __restrict__ srcs,
                            const float* __restrict__ dinv) {
  int i = blockIdx.x * 8 + (threadIdx.x >> 5);
  int l = threadIdx.x & 31;
  int e0 = off[i], e1 = off[i + 1];
  float a[8] = {};
  for (int e = e0; e < e1; ++e) {
    int j = srcs[e];
    float dj = dinv[j];
    u16x8 u = *(const u16x8*)(in + (size_t)j * 256 + l * 8);
#pragma unroll
    for (int k = 0; k < 8; ++k) a[k] = fmaf(dj, bf2f(u[k]), a[k]);
  }
  float di = dinv[i];
  u16x8 o;
#pragma unroll
  for (int k = 0; k < 8; ++k) o[k] = f2bf(a[k] * di);
  *(u16x8*)(out + (size_t)i * 256 + l * 8) = o;
}

// ---- propagate + bias + relu (bf16 -> f32), sorted in -> ORIGINAL-order out ----
__global__ void prop2_kernel(const unsigned short* __restrict__ in,
                             float* __restrict__ out,
                             const int* __restrict__ off, const int* __restrict__ srcs,
                             const float* __restrict__ dinv, const float* __restrict__ bias,
                             const unsigned long long* __restrict__ skeys) {
  int i = blockIdx.x * 8 + (threadIdx.x >> 5);
  int l = threadIdx.x & 31;
  int e0 = off[i], e1 = off[i + 1];
  float a[8] = {};
  for (int e = e0; e < e1; ++e) {
    int j = srcs[e];
    float dj = dinv[j];
    u16x8 u = *(const u16x8*)(in + (size_t)j * 256 + l * 8);
#pragma unroll
    for (int k = 0; k < 8; ++k) a[k] = fmaf(dj, bf2f(u[k]), a[k]);
  }
  float di = dinv[i];
  // un-permute: original node row for this sorted position
  int node = (i & ~(NPB - 1)) + (int)(skeys[i] & 0xffffffffull);
  float4 o0, o1;
  o0.x = fmaxf(a[0] * di + bias[l * 8 + 0], 0.f);
  o0.y = fmaxf(a[1] * di + bias[l * 8 + 1], 0.f);
  o0.z = fmaxf(a[2] * di + bias[l * 8 + 2], 0.f);
  o0.w = fmaxf(a[3] * di + bias[l * 8 + 3], 0.f);
  o1.x = fmaxf(a[4] * di + bias[l * 8 + 4], 0.f);
  o1.y = fmaxf(a[5] * di + bias[l * 8 + 5], 0.f);
  o1.z = fmaxf(a[6] * di + bias[l * 8 + 6], 0.f);
  o1.w = fmaxf(a[7] * di + bias[l * 8 + 7], 0.f);
  *(float4*)(out + (size_t)node * 256 + l * 8) = o0;
  *(float4*)(out + (size_t)node * 256 + l * 8 + 4) = o1;
}

// ---- bf16 MFMA GEMM: C[M,N] = A[M,K] @ Bt[N,K]^T (+bias, relu), 64x128 tile ----
template <bool BIAS_RELU, bool OUT_BF16>
__global__ __launch_bounds__(256)
void gemm_bf16_kernel(const unsigned short* __restrict__ A,
                      const unsigned short* __restrict__ Bt,
                      void* __restrict__ C, const float* __restrict__ bias,
                      int M, int N, int K) {
  __shared__ char lds[24576];   // A: [64][128B] @0 ; B: [128][128B] @8192
  const int tid = threadIdx.x;
  const int l = tid & 63, w = tid >> 6;
  const int bm = blockIdx.x * 64, bn = blockIdx.y * 128;
  f32x4 acc[4][2] = {};

  for (int k0 = 0; k0 < K; k0 += 64) {
    __syncthreads();
#pragma unroll
    for (int q = 0; q < 2; ++q) {
      int o = q * 4096 + tid * 16;
      int r = o >> 7;
      int gc = ((o >> 4) & 7) ^ (r & 7);
      const char* srcA = (const char*)A + ((size_t)(bm + r) * K + k0) * 2 + gc * 16;
      __builtin_amdgcn_global_load_lds(
          (const __attribute__((address_space(1))) void*)srcA,
          (__attribute__((address_space(3))) void*)(lds + o), 16, 0, 0);
    }
#pragma unroll
    for (int q = 0; q < 4; ++q) {
      int o = q * 4096 + tid * 16;
      int r = o >> 7;
      int gc = ((o >> 4) & 7) ^ (r & 7);
      const char* srcB = (const char*)Bt + ((size_t)(bn + r) * K + k0) * 2 + gc * 16;
      __builtin_amdgcn_global_load_lds(
          (const __attribute__((address_space(1))) void*)srcB,
          (__attribute__((address_space(3))) void*)(lds + 8192 + o), 16, 0, 0);
    }
    __syncthreads();

#pragma unroll
    for (int kk = 0; kk < 64; kk += 32) {
      bf16x8 af[4], bf[2];
      int gc = (kk >> 3) + (l >> 4);
#pragma unroll
      for (int mi = 0; mi < 4; ++mi) {
        int r = mi * 16 + (l & 15);
        af[mi] = *(const bf16x8*)(lds + r * 128 + ((gc ^ (r & 7)) << 4));
      }
#pragma unroll
      for (int ni = 0; ni < 2; ++ni) {
        int r = w * 32 + ni * 16 + (l & 15);
        bf[ni] = *(const bf16x8*)(lds + 8192 + r * 128 + ((gc ^ (r & 7)) << 4));
      }
#pragma unroll
      for (int mi = 0; mi < 4; ++mi)
#pragma unroll
        for (int ni = 0; ni < 2; ++ni)
          acc[mi][ni] = __builtin_amdgcn_mfma_f32_16x16x32_bf16(af[mi], bf[ni],
                                                                acc[mi][ni], 0, 0, 0);
    }
  }

#pragma unroll
  for (int mi = 0; mi < 4; ++mi) {
#pragma unroll
    for (int ni = 0; ni < 2; ++ni) {
      int row0 = bm + mi * 16 + ((l >> 4) << 2);
      int col = bn + w * 32 + ni * 16 + (l & 15);
      float bv = BIAS_RELU ? bias[col] : 0.f;
      f32x4 v = acc[mi][ni];
#pragma unroll
      for (int r = 0; r < 4; ++r) {
        float val = v[r];
        if (BIAS_RELU) val = fmaxf(val + bv, 0.f);
        if (OUT_BF16)
          ((unsigned short*)C)[(size_t)(row0 + r) * N + col] = f2bf(val);
        else
          ((float*)C)[(size_t)(row0 + r) * N + col] = val;
      }
    }
  }
}

// ---- launch ----
extern "C" void kernel_launch(void* const* d_in, const int* in_sizes, int n_in,
                              void* d_out, int out_size, void* d_ws, size_t ws_size,
                              hipStream_t stream) {
  const float* dm = (const float*)d_in[0];
  const float* fm = (const float*)d_in[1];
  const float* W1 = (const float*)d_in[2];
  const float* b1 = (const float*)d_in[3];
  const float* W2 = (const float*)d_in[4];
  const float* b2 = (const float*)d_in[5];
  float* out = (float*)d_out;

  char* ws = (char*)d_ws;
  int*                tgt   = (int*)(ws + 0x000000);               // 256KB
  int*                deg   = (int*)(ws + 0x040000);               // 64KB
  float*              dinv  = (float*)(ws + 0x050000);             // 64KB
  int*                off   = (int*)(ws + 0x060000);               // 64KB+4
  int*                cur   = (int*)(ws + 0x080000);               // 64KB+4
  int*                srcs  = (int*)(ws + 0x0A0000);               // 320KB
  unsigned long long* skeys = (unsigned long long*)(ws + 0x100000);// 128KB
  int*                rank  = (int*)(ws + 0x130000);               // 64KB
  unsigned short*     W1t   = (unsigned short*)(ws + 0x190000);    // 256KB
  unsigned short*     W2t   = (unsigned short*)(ws + 0x1D0000);    // 256KB
  unsigned short*     px0   = (unsigned short*)(ws + 0x0400000);   // 8MB (sorted space)
  unsigned short*     px    = (unsigned short*)(ws + 0x0C00000);   // 8MB (sorted space)
  unsigned short*     h1    = (unsigned short*)(ws + 0x1400000);   // 16MB (sorted space)
  unsigned short*     t2    = (unsigned short*)(ws + 0x2400000);   // 8MB (sorted space)
  float*              xout  = (float*)(ws + 0x2C00000);            // 16MB (original order)
  (void)ws_size; (void)in_sizes; (void)n_in; (void)out_size;

  // ---- graph build in sorted-position space: 4 kernels ----
  bucket_kernel<<<NB, 1024, 0, stream>>>(dm, skeys, rank, deg);
  knn_select_kernel<<<64, 256, 0, stream>>>(skeys, tgt, deg);
  scan_kernel<<<1, 256, 0, stream>>>(deg, dinv, off, cur);
  fill_csr_kernel<<<NEDGE / 256, 256, 0, stream>>>(tgt, cur, srcs);

  // ---- conversions: fm -> sorted-space bf16 rows; weights -> [N][K] bf16 ----
  cvt_all_kernel<<<dim3(128, 4, NB + 1), 256, 0, stream>>>(fm, px0, W1, W1t, W2, W2t, rank);

  // layer 1 (sorted space): window propagate, then GEMM relu(.@W1+b1) -> bf16
  prop_kernel<<<N_NODES / 8, 256, 0, stream>>>(px0, px, off, srcs, dinv);
  gemm_bf16_kernel<true, true><<<dim3(256, 4), 256, 0, stream>>>(
      px, W1t, h1, b1, 16384, 512, 256);

  // layer 2: GEMM h1@W2 -> bf16 (sorted), window propagate + un-permute -> f32
  gemm_bf16_kernel<false, true><<<dim3(256, 2), 256, 0, stream>>>(
      h1, W2t, t2, nullptr, 16384, 256, 512);
  prop2_kernel<<<N_NODES / 8, 256, 0, stream>>>(t2, xout, off, srcs, dinv, b2, skeys);

  // node-major -> [B][256][4096]
  transpose_kernel<<<dim3(8, 128, NB), 256, 0, stream>>>(xout, out, 4096, 256);
}

// Round 18
// 88.856 us; speedup vs baseline: 1.1988x; 1.0758x over previous
//
#include <hip/hip_runtime.h>
#include <hip/hip_bf16.h>
#include <stdint.h>

#define N_NODES 16384   // B*H*W
#define NPB     4096    // nodes per batch
#define NB      4
#define KNN     4
#define WIN     12      // sorted-order window radius for exact 1-D kNN
#define NBUK    4096

typedef short bf16x8 __attribute__((ext_vector_type(8)));
typedef float f32x4 __attribute__((ext_vector_type(4)));
typedef unsigned short u16x8 __attribute__((ext_vector_type(8)));

__device__ __forceinline__ unsigned short f2bf(float f) {
  unsigned u = __float_as_uint(f);
  unsigned r = (u + 0x7fff + ((u >> 16) & 1)) >> 16;   // RNE
  return (unsigned short)r;
}
__device__ __forceinline__ float bf2f(unsigned short u) {
  return __uint_as_float(((unsigned)u) << 16);
}

// ---- fused bucket stage: hist + scan + scatter + in-LDS bucket sort ----
// One block per batch (4 x 1024). Emits sorted per-batch skeys AND rank.
__global__ __launch_bounds__(1024)
void bucket_kernel(const float* __restrict__ dm,
                   unsigned long long* __restrict__ skeys_g,
                   int* __restrict__ rank_g,
                   int* __restrict__ deg) {
  __shared__ int sHist[4096];
  __shared__ int sCur[4096];
  __shared__ unsigned long long sKeys[4096];  // aliases part1/part2 (scan scratch)
  int* part1 = (int*)sKeys;                   // [1024]
  int* part2 = (int*)(sKeys + 512);           // [64]
  const int t = threadIdx.x, b = blockIdx.x;
  const float* d = dm + b * NPB;

  unsigned long long kv[4]; int bk[4];
#pragma unroll
  for (int r = 0; r < 4; ++r) {
    int i = t + r * 1024;
    sHist[i] = 0;
    deg[b * NPB + i] = 1;   // deg indexed by sorted position; self-loop
  }
  __syncthreads();
#pragma unroll
  for (int r = 0; r < 4; ++r) {
    int i = t + r * 1024;
    float v = d[i];
    kv[r] = (((unsigned long long)__float_as_uint(v)) << 32) | (unsigned)i;
    int k = (int)(v * (float)NBUK); if (k > NBUK - 1) k = NBUK - 1;
    bk[r] = k;
    atomicAdd(&sHist[k], 1);
  }
  __syncthreads();
  int c0 = sHist[4 * t + 0], c1 = sHist[4 * t + 1];
  int c2 = sHist[4 * t + 2], c3 = sHist[4 * t + 3];
  part1[t] = c0 + c1 + c2 + c3;
  __syncthreads();
  if (t < 64) {
    int s = 0;
#pragma unroll
    for (int k = 0; k < 16; ++k) s += part1[16 * t + k];
    part2[t] = s;
  }
  __syncthreads();
  if (t == 0) {
    int a = 0;
    for (int u = 0; u < 64; ++u) { int v = part2[u]; part2[u] = a; a += v; }
  }
  __syncthreads();
  int base = part2[t >> 4];
  for (int k = (t >> 4) * 16; k < t; ++k) base += part1[k];
  sHist[4 * t + 0] = base; sCur[4 * t + 0] = base; base += c0;
  sHist[4 * t + 1] = base; sCur[4 * t + 1] = base; base += c1;
  sHist[4 * t + 2] = base; sCur[4 * t + 2] = base; base += c2;
  sHist[4 * t + 3] = base; sCur[4 * t + 3] = base;
  __syncthreads();   // scan scratch dead -> sKeys writable
#pragma unroll
  for (int r = 0; r < 4; ++r) {
    int slot = atomicAdd(&sCur[bk[r]], 1);
    sKeys[slot] = kv[r];
  }
  __syncthreads();
#pragma unroll
  for (int r = 0; r < 4; ++r) {
    int g = t + r * 1024;
    int s0 = sHist[g];
    int s1 = (g == NPB - 1) ? NPB : sHist[g + 1];
    for (int i = s0 + 1; i < s1; ++i) {
      unsigned long long x = sKeys[i];
      int j = i - 1;
      while (j >= s0 && sKeys[j] > x) { sKeys[j + 1] = sKeys[j]; --j; }
      sKeys[j + 1] = x;
    }
  }
  __syncthreads();
#pragma unroll
  for (int r = 0; r < 4; ++r) {
    int i = t + r * 1024;
    unsigned long long k = sKeys[i];
    skeys_g[b * NPB + i] = k;
    rank_g[b * NPB + (int)(k & 0xffffffffull)] = i;   // batch-local position
  }
}

// ---- kNN select in SORTED-POSITION space ----
// dk = (dist<<24)|(idx<<12)|pos : (dist, idx) lexicographic; pos is payload.
__global__ void knn_select_kernel(const unsigned long long* __restrict__ skeys,
                                  int* __restrict__ tgt, int* __restrict__ deg) {
  int p = blockIdx.x * 256 + threadIdx.x;   // global sorted slot
  if (p >= N_NODES) return;
  int b = p >> 12, pl = p & (NPB - 1);
  const unsigned long long* sk = skeys + b * NPB;
  unsigned long long kp = sk[pl];
  float di = __uint_as_float((unsigned)(kp >> 32));
  int lo = pl - WIN; if (lo < 0) lo = 0;
  int hi = pl + WIN; if (hi > NPB - 1) hi = NPB - 1;
  unsigned long long k0 = ~0ull, k1 = ~0ull, k2 = ~0ull, k3 = ~0ull, k4 = ~0ull;
  for (int q = lo; q <= hi; ++q) {
    unsigned long long key = sk[q];
    float v = __uint_as_float((unsigned)(key >> 32));
    float dist = fabsf(di - v);
    unsigned long long dk = (((unsigned long long)__float_as_uint(dist)) << 24) |
                            ((key & 0xfffull) << 12) | (unsigned)q;
    if (dk < k4) {
      if (dk < k0)      { k4 = k3; k3 = k2; k2 = k1; k1 = k0; k0 = dk; }
      else if (dk < k1) { k4 = k3; k3 = k2; k2 = k1; k1 = dk; }
      else if (dk < k2) { k4 = k3; k3 = k2; k2 = dk; }
      else if (dk < k3) { k4 = k3; k3 = dk; }
      else              { k4 = dk; }
    }
  }
  int base = b * NPB;
  int t0 = base + (int)(k1 & 0xfff);
  int t1 = base + (int)(k2 & 0xfff);
  int t2 = base + (int)(k3 & 0xfff);
  int t3 = base + (int)(k4 & 0xfff);
  tgt[p * KNN + 0] = t0; atomicAdd(&deg[t0], 1);
  tgt[p * KNN + 1] = t1; atomicAdd(&deg[t1], 1);
  tgt[p * KNN + 2] = t2; atomicAdd(&deg[t2], 1);
  tgt[p * KNN + 3] = t3; atomicAdd(&deg[t3], 1);
}

// ---- combined cvt with 128B bf16 stores + PERMUTED node rows ----
__global__ void cvt_all_kernel(const float* __restrict__ fm, unsigned short* __restrict__ px0,
                               const float* __restrict__ W1, unsigned short* __restrict__ W1t,
                               const float* __restrict__ W2, unsigned short* __restrict__ W2t,
                               const int* __restrict__ rank) {
  __shared__ float tile[64][33];
  int z = blockIdx.z;
  const float* in; unsigned short* outbase; int Rin, Cin, r0, c0;
  bool perm = false;
  if (z < NB) {
    in = fm + (size_t)z * 256 * 4096; outbase = px0 + (size_t)z * NPB * 256;
    Rin = 256; Cin = 4096; perm = true;
    c0 = blockIdx.x * 32; r0 = blockIdx.y * 64;
  } else {
    int id = blockIdx.y * 128 + blockIdx.x;
    if (id < 64)       { in = W1; outbase = W1t; Rin = 256; Cin = 512; c0 = (id & 15) * 32; r0 = (id >> 4) * 64; }
    else if (id < 128) { id -= 64; in = W2; outbase = W2t; Rin = 512; Cin = 256; c0 = (id & 7) * 32; r0 = (id >> 3) * 64; }
    else return;
  }
  int tx = threadIdx.x & 31, ty = threadIdx.x >> 5;   // ty 0..7
  const float* ip = in + (size_t)(r0 + ty) * Cin + c0 + tx;
#pragma unroll
  for (int i = 0; i < 8; ++i) tile[ty + 8 * i][tx] = ip[(size_t)(8 * i) * Cin];
  __syncthreads();
  int orow = threadIdx.x >> 3;        // 0..31 (input col / node)
  int oseg = (threadIdx.x & 7) * 8;   // 0..56 (input row offset)
  int outrow = c0 + orow;
  if (perm) outrow = rank[(size_t)z * NPB + outrow];
  unsigned short* op = outbase + (size_t)outrow * Rin + r0 + oseg;
  u16x8 o;
#pragma unroll
  for (int k = 0; k < 8; ++k) o[k] = f2bf(tile[oseg + k][orow]);
  *(u16x8*)op = o;
}

// ---- fp32 batched transpose: [B][Rin][Cin] -> [B][Cin][Rin] ----
__global__ void transpose_kernel(const float* __restrict__ in, float* __restrict__ out,
                                 int Rin, int Cin) {
  __shared__ float tile[32][33];
  int c0 = blockIdx.x * 32, r0 = blockIdx.y * 32, b = blockIdx.z;
  int tx = threadIdx.x & 31, ty = threadIdx.x >> 5;
  const float* ip = in + ((size_t)b * Rin + r0) * Cin + c0;
#pragma unroll
  for (int i = 0; i < 32; i += 8) tile[ty + i][tx] = ip[(size_t)(ty + i) * Cin + tx];
  __syncthreads();
  float* op = out + ((size_t)b * Cin + c0) * Rin + r0;
#pragma unroll
  for (int i = 0; i < 32; i += 8) op[(size_t)(ty + i) * Rin + tx] = tile[tx][ty + i];
}

// ---- propagate via direct window scan (CSR-free), 2 nodes/wave ----
// Incoming edges of position i are exactly {q in [i+-12] : i in tgt[q]} with
// MULTIPLICITY (self loop q==i counts too; a tie can make i its own kNN
// target -> count 2, matching the reference's concatenated edge list).
__global__ void prop_kernel(const unsigned short* __restrict__ in,
                            unsigned short* __restrict__ out,
                            const int* __restrict__ tgt, const int* __restrict__ deg) {
  int i = blockIdx.x * 8 + (threadIdx.x >> 5);
  int l = threadIdx.x & 31;
  int b0 = i & ~(NPB - 1);
  int lo = i - WIN; if (lo < b0) lo = b0;
  int hi = i + WIN; if (hi > b0 + NPB - 1) hi = b0 + NPB - 1;
  float a[8] = {};
  for (int q = lo; q <= hi; ++q) {
    int4 tq = *(const int4*)(tgt + q * 4);
    int c = (q == i) + (tq.x == i) + (tq.y == i) + (tq.z == i) + (tq.w == i);
    if (c) {
      float dj = (float)c * rsqrtf((float)deg[q]);
      u16x8 u = *(const u16x8*)(in + (size_t)q * 256 + l * 8);
#pragma unroll
      for (int k = 0; k < 8; ++k) a[k] = fmaf(dj, bf2f(u[k]), a[k]);
    }
  }
  float di = rsqrtf((float)deg[i]);
  u16x8 o;
#pragma unroll
  for (int k = 0; k < 8; ++k) o[k] = f2bf(a[k] * di);
  *(u16x8*)(out + (size_t)i * 256 + l * 8) = o;
}

// ---- window propagate + bias + relu, sorted in -> ORIGINAL-order f32 out ----
__global__ void prop2_kernel(const unsigned short* __restrict__ in,
                             float* __restrict__ out,
                             const int* __restrict__ tgt, const int* __restrict__ deg,
                             const float* __restrict__ bias,
                             const unsigned long long* __restrict__ skeys) {
  int i = blockIdx.x * 8 + (threadIdx.x >> 5);
  int l = threadIdx.x & 31;
  int b0 = i & ~(NPB - 1);
  int lo = i - WIN; if (lo < b0) lo = b0;
  int hi = i + WIN; if (hi > b0 + NPB - 1) hi = b0 + NPB - 1;
  float a[8] = {};
  for (int q = lo; q <= hi; ++q) {
    int4 tq = *(const int4*)(tgt + q * 4);
    int c = (q == i) + (tq.x == i) + (tq.y == i) + (tq.z == i) + (tq.w == i);
    if (c) {
      float dj = (float)c * rsqrtf((float)deg[q]);
      u16x8 u = *(const u16x8*)(in + (size_t)q * 256 + l * 8);
#pragma unroll
      for (int k = 0; k < 8; ++k) a[k] = fmaf(dj, bf2f(u[k]), a[k]);
    }
  }
  float di = rsqrtf((float)deg[i]);
  int node = b0 + (int)(skeys[i] & 0xffffffffull);   // un-permute
  float4 o0, o1;
  o0.x = fmaxf(a[0] * di + bias[l * 8 + 0], 0.f);
  o0.y = fmaxf(a[1] * di + bias[l * 8 + 1], 0.f);
  o0.z = fmaxf(a[2] * di + bias[l * 8 + 2], 0.f);
  o0.w = fmaxf(a[3] * di + bias[l * 8 + 3], 0.f);
  o1.x = fmaxf(a[4] * di + bias[l * 8 + 4], 0.f);
  o1.y = fmaxf(a[5] * di + bias[l * 8 + 5], 0.f);
  o1.z = fmaxf(a[6] * di + bias[l * 8 + 6], 0.f);
  o1.w = fmaxf(a[7] * di + bias[l * 8 + 7], 0.f);
  *(float4*)(out + (size_t)node * 256 + l * 8) = o0;
  *(float4*)(out + (size_t)node * 256 + l * 8 + 4) = o1;
}

// ---- bf16 MFMA GEMM: C[M,N] = A[M,K] @ Bt[N,K]^T, 64 x (64*NI) tile ----
// NI = 16-col fragments per wave (2 -> 128-wide tile, 1 -> 64-wide tile).
template <bool BIAS_RELU, bool OUT_BF16, int NI>
__global__ __launch_bounds__(256)
void gemm_bf16_kernel(const unsigned short* __restrict__ A,
                      const unsigned short* __restrict__ Bt,
                      void* __restrict__ C, const float* __restrict__ bias,
                      int M, int N, int K) {
  __shared__ char lds[8192 + NI * 8192];   // A: [64][128B] @0 ; B: [64*NI][128B] @8192
  const int tid = threadIdx.x;
  const int l = tid & 63, w = tid >> 6;
  const int bm = blockIdx.x * 64, bn = blockIdx.y * (64 * NI);
  f32x4 acc[4][NI] = {};

  for (int k0 = 0; k0 < K; k0 += 64) {
    __syncthreads();
#pragma unroll
    for (int q = 0; q < 2; ++q) {          // A tile: 8KB
      int o = q * 4096 + tid * 16;
      int r = o >> 7;
      int gc = ((o >> 4) & 7) ^ (r & 7);
      const char* srcA = (const char*)A + ((size_t)(bm + r) * K + k0) * 2 + gc * 16;
      __builtin_amdgcn_global_load_lds(
          (const __attribute__((address_space(1))) void*)srcA,
          (__attribute__((address_space(3))) void*)(lds + o), 16, 0, 0);
    }
#pragma unroll
    for (int q = 0; q < 2 * NI; ++q) {     // B tile: NI*8KB
      int o = q * 4096 + tid * 16;
      int r = o >> 7;
      int gc = ((o >> 4) & 7) ^ (r & 7);
      const char* srcB = (const char*)Bt + ((size_t)(bn + r) * K + k0) * 2 + gc * 16;
      __builtin_amdgcn_global_load_lds(
          (const __attribute__((address_space(1))) void*)srcB,
          (__attribute__((address_space(3))) void*)(lds + 8192 + o), 16, 0, 0);
    }
    __syncthreads();

#pragma unroll
    for (int kk = 0; kk < 64; kk += 32) {
      bf16x8 af[4], bf[NI];
      int gc = (kk >> 3) + (l >> 4);
#pragma unroll
      for (int mi = 0; mi < 4; ++mi) {
        int r = mi * 16 + (l & 15);
        af[mi] = *(const bf16x8*)(lds + r * 128 + ((gc ^ (r & 7)) << 4));
      }
#pragma unroll
      for (int ni = 0; ni < NI; ++ni) {
        int r = w * (16 * NI) + ni * 16 + (l & 15);
        bf[ni] = *(const bf16x8*)(lds + 8192 + r * 128 + ((gc ^ (r & 7)) << 4));
      }
#pragma unroll
      for (int mi = 0; mi < 4; ++mi)
#pragma unroll
        for (int ni = 0; ni < NI; ++ni)
          acc[mi][ni] = __builtin_amdgcn_mfma_f32_16x16x32_bf16(af[mi], bf[ni],
                                                                acc[mi][ni], 0, 0, 0);
    }
  }

#pragma unroll
  for (int mi = 0; mi < 4; ++mi) {
#pragma unroll
    for (int ni = 0; ni < NI; ++ni) {
      int row0 = bm + mi * 16 + ((l >> 4) << 2);
      int col = bn + w * (16 * NI) + ni * 16 + (l & 15);
      float bv = BIAS_RELU ? bias[col] : 0.f;
      f32x4 v = acc[mi][ni];
#pragma unroll
      for (int r = 0; r < 4; ++r) {
        float val = v[r];
        if (BIAS_RELU) val = fmaxf(val + bv, 0.f);
        if (OUT_BF16)
          ((unsigned short*)C)[(size_t)(row0 + r) * N + col] = f2bf(val);
        else
          ((float*)C)[(size_t)(row0 + r) * N + col] = val;
      }
    }
  }
}

// ---- launch ----
extern "C" void kernel_launch(void* const* d_in, const int* in_sizes, int n_in,
                              void* d_out, int out_size, void* d_ws, size_t ws_size,
                              hipStream_t stream) {
  const float* dm = (const float*)d_in[0];
  const float* fm = (const float*)d_in[1];
  const float* W1 = (const float*)d_in[2];
  const float* b1 = (const float*)d_in[3];
  const float* W2 = (const float*)d_in[4];
  const float* b2 = (const float*)d_in[5];
  float* out = (float*)d_out;

  char* ws = (char*)d_ws;
  int*                tgt   = (int*)(ws + 0x000000);               // 256KB
  int*                deg   = (int*)(ws + 0x040000);               // 64KB
  unsigned long long* skeys = (unsigned long long*)(ws + 0x100000);// 128KB
  int*                rank  = (int*)(ws + 0x130000);               // 64KB
  unsigned short*     W1t   = (unsigned short*)(ws + 0x190000);    // 256KB
  unsigned short*     W2t   = (unsigned short*)(ws + 0x1D0000);    // 256KB
  unsigned short*     px0   = (unsigned short*)(ws + 0x0400000);   // 8MB (sorted space)
  unsigned short*     px    = (unsigned short*)(ws + 0x0C00000);   // 8MB (sorted space)
  unsigned short*     h1    = (unsigned short*)(ws + 0x1400000);   // 16MB (sorted space)
  unsigned short*     t2    = (unsigned short*)(ws + 0x2400000);   // 8MB (sorted space)
  float*              xout  = (float*)(ws + 0x2C00000);            // 16MB (original order)
  (void)ws_size; (void)in_sizes; (void)n_in; (void)out_size;

  // ---- graph build in sorted-position space: 2 kernels (CSR-free) ----
  bucket_kernel<<<NB, 1024, 0, stream>>>(dm, skeys, rank, deg);
  knn_select_kernel<<<64, 256, 0, stream>>>(skeys, tgt, deg);

  // ---- conversions: fm -> sorted-space bf16 rows; weights -> [N][K] bf16 ----
  cvt_all_kernel<<<dim3(128, 4, NB + 1), 256, 0, stream>>>(fm, px0, W1, W1t, W2, W2t, rank);

  // layer 1 (sorted space): window propagate, then GEMM relu(.@W1+b1) -> bf16
  prop_kernel<<<N_NODES / 8, 256, 0, stream>>>(px0, px, tgt, deg);
  gemm_bf16_kernel<true, true, 2><<<dim3(256, 4), 256, 0, stream>>>(
      px, W1t, h1, b1, 16384, 512, 256);

  // layer 2: GEMM h1@W2 -> bf16 (64x64 tile, 1024 blocks), window prop + un-permute
  gemm_bf16_kernel<false, true, 1><<<dim3(256, 4), 256, 0, stream>>>(
      h1, W2t, t2, nullptr, 16384, 256, 512);
  prop2_kernel<<<N_NODES / 8, 256, 0, stream>>>(t2, xout, tgt, deg, b2, skeys);

  // node-major -> [B][256][4096]
  transpose_kernel<<<dim3(8, 128, NB), 256, 0, stream>>>(xout, out, 4096, 256);
}

// Round 20
// 82.170 us; speedup vs baseline: 1.2963x; 1.0814x over previous
//
#include <hip/hip_runtime.h>
#include <hip/hip_bf16.h>
#include <stdint.h>

#define N_NODES 16384   // B*H*W
#define NPB     4096    // nodes per batch
#define NB      4
#define KNN     4
#define WIN     12      // sorted-order window radius for exact 1-D kNN
#define NBUK    4096

typedef short bf16x8 __attribute__((ext_vector_type(8)));
typedef float f32x4 __attribute__((ext_vector_type(4)));
typedef unsigned short u16x8 __attribute__((ext_vector_type(8)));

__device__ __forceinline__ unsigned short f2bf(float f) {
  unsigned u = __float_as_uint(f);
  unsigned r = (u + 0x7fff + ((u >> 16) & 1)) >> 16;   // RNE
  return (unsigned short)r;
}
__device__ __forceinline__ float bf2f(unsigned short u) {
  return __uint_as_float(((unsigned)u) << 16);
}

// ---- fused graph build: hist + scan + scatter + sort + SELECT + deg + mask ----
// One block per batch (4 x 1024). All stages LDS-resident (80KB).
// Outputs: skeys (sorted (value,idx) keys), rank (node -> position),
// dinv (rsqrt degree per position), mask (25-bit incoming-edge window mask).
__global__ __launch_bounds__(1024)
void bucket_kernel(const float* __restrict__ dm,
                   unsigned long long* __restrict__ skeys_g,
                   int* __restrict__ rank_g,
                   float* __restrict__ dinv_g,
                   unsigned* __restrict__ mask_g) {
  __shared__ int sHist[4096];                 // hist -> starts -> (reuse) deg
  __shared__ int sCur[4096];                  // scatter cursors
  __shared__ unsigned long long sKeys[4096];  // sorted keys (32KB); aliases scan scratch
  __shared__ unsigned sMask[4096];            // incoming-edge window masks
  int* part1 = (int*)sKeys;                   // [1024]
  int* part2 = (int*)(sKeys + 512);           // [64]
  const int t = threadIdx.x, b = blockIdx.x;
  const float* d = dm + b * NPB;

  unsigned long long kv[4]; int bk[4];
#pragma unroll
  for (int r = 0; r < 4; ++r) sHist[t + r * 1024] = 0;
  __syncthreads();
#pragma unroll
  for (int r = 0; r < 4; ++r) {
    int i = t + r * 1024;
    float v = d[i];
    kv[r] = (((unsigned long long)__float_as_uint(v)) << 32) | (unsigned)i;
    int k = (int)(v * (float)NBUK); if (k > NBUK - 1) k = NBUK - 1;
    bk[r] = k;
    atomicAdd(&sHist[k], 1);
  }
  __syncthreads();
  // exclusive scan of bucket counts (scratch aliases sKeys; consumed pre-scatter)
  int c0 = sHist[4 * t + 0], c1 = sHist[4 * t + 1];
  int c2 = sHist[4 * t + 2], c3 = sHist[4 * t + 3];
  part1[t] = c0 + c1 + c2 + c3;
  __syncthreads();
  if (t < 64) {
    int s = 0;
#pragma unroll
    for (int k = 0; k < 16; ++k) s += part1[16 * t + k];
    part2[t] = s;
  }
  __syncthreads();
  if (t == 0) {
    int a = 0;
    for (int u = 0; u < 64; ++u) { int v = part2[u]; part2[u] = a; a += v; }
  }
  __syncthreads();
  int base = part2[t >> 4];
  for (int k = (t >> 4) * 16; k < t; ++k) base += part1[k];
  sHist[4 * t + 0] = base; sCur[4 * t + 0] = base; base += c0;
  sHist[4 * t + 1] = base; sCur[4 * t + 1] = base; base += c1;
  sHist[4 * t + 2] = base; sCur[4 * t + 2] = base; base += c2;
  sHist[4 * t + 3] = base; sCur[4 * t + 3] = base;
  __syncthreads();   // scan scratch dead -> sKeys writable
#pragma unroll
  for (int r = 0; r < 4; ++r) {
    int slot = atomicAdd(&sCur[bk[r]], 1);
    sKeys[slot] = kv[r];
  }
  __syncthreads();
  // per-bucket insertion sort -> exact (value,idx) order
#pragma unroll
  for (int r = 0; r < 4; ++r) {
    int g = t + r * 1024;
    int s0 = sHist[g];
    int s1 = (g == NPB - 1) ? NPB : sHist[g + 1];
    for (int i = s0 + 1; i < s1; ++i) {
      unsigned long long x = sKeys[i];
      int j = i - 1;
      while (j >= s0 && sKeys[j] > x) { sKeys[j + 1] = sKeys[j]; --j; }
      sKeys[j + 1] = x;
    }
  }
  __syncthreads();
  // reinit: sHist = deg (self loop), sMask = 0
#pragma unroll
  for (int r = 0; r < 4; ++r) {
    int i = t + r * 1024;
    sHist[i] = 1;
    sMask[i] = 0;
  }
  __syncthreads();
  // windowed exact top-5 by (dist,idx); accumulate deg + incoming-edge masks.
  // dk = (dist<<24)|(idx<<12)|pos -- (dist,idx) lexicographic, pos is payload.
#pragma unroll
  for (int r = 0; r < 4; ++r) {
    int p = t + r * 1024;                 // batch-local sorted position
    unsigned long long kp = sKeys[p];
    float di = __uint_as_float((unsigned)(kp >> 32));
    int lo = p - WIN; if (lo < 0) lo = 0;
    int hi = p + WIN; if (hi > NPB - 1) hi = NPB - 1;
    unsigned long long k0 = ~0ull, k1 = ~0ull, k2 = ~0ull, k3 = ~0ull, k4 = ~0ull;
    for (int q = lo; q <= hi; ++q) {
      unsigned long long key = sKeys[q];
      float v = __uint_as_float((unsigned)(key >> 32));
      float dist = fabsf(di - v);
      unsigned long long dk = (((unsigned long long)__float_as_uint(dist)) << 24) |
                              ((key & 0xfffull) << 12) | (unsigned)q;
      if (dk < k4) {
        if (dk < k0)      { k4 = k3; k3 = k2; k2 = k1; k1 = k0; k0 = dk; }
        else if (dk < k1) { k4 = k3; k3 = k2; k2 = k1; k1 = dk; }
        else if (dk < k2) { k4 = k3; k3 = k2; k2 = dk; }
        else if (dk < k3) { k4 = k3; k3 = dk; }
        else              { k4 = dk; }
      }
    }
    int t0 = (int)(k1 & 0xfff), t1 = (int)(k2 & 0xfff);
    int t2 = (int)(k3 & 0xfff), t3 = (int)(k4 & 0xfff);
    atomicAdd(&sHist[t0], 1); atomicOr(&sMask[t0], 1u << (p - t0 + WIN));
    atomicAdd(&sHist[t1], 1); atomicOr(&sMask[t1], 1u << (p - t1 + WIN));
    atomicAdd(&sHist[t2], 1); atomicOr(&sMask[t2], 1u << (p - t2 + WIN));
    atomicAdd(&sHist[t3], 1); atomicOr(&sMask[t3], 1u << (p - t3 + WIN));
  }
  __syncthreads();
  // global writes: skeys, rank, dinv, mask
#pragma unroll
  for (int r = 0; r < 4; ++r) {
    int i = t + r * 1024;
    unsigned long long k = sKeys[i];
    skeys_g[b * NPB + i] = k;
    rank_g[b * NPB + (int)(k & 0xffffffffull)] = i;
    dinv_g[b * NPB + i] = rsqrtf((float)sHist[i]);
    mask_g[b * NPB + i] = sMask[i];
  }
}

// ---- combined cvt with 128B bf16 stores + PERMUTED node rows ----
__global__ void cvt_all_kernel(const float* __restrict__ fm, unsigned short* __restrict__ px0,
                               const float* __restrict__ W1, unsigned short* __restrict__ W1t,
                               const float* __restrict__ W2, unsigned short* __restrict__ W2t,
                               const int* __restrict__ rank) {
  __shared__ float tile[64][33];
  int z = blockIdx.z;
  const float* in; unsigned short* outbase; int Rin, Cin, r0, c0;
  bool perm = false;
  if (z < NB) {
    in = fm + (size_t)z * 256 * 4096; outbase = px0 + (size_t)z * NPB * 256;
    Rin = 256; Cin = 4096; perm = true;
    c0 = blockIdx.x * 32; r0 = blockIdx.y * 64;
  } else {
    int id = blockIdx.y * 128 + blockIdx.x;
    if (id < 64)       { in = W1; outbase = W1t; Rin = 256; Cin = 512; c0 = (id & 15) * 32; r0 = (id >> 4) * 64; }
    else if (id < 128) { id -= 64; in = W2; outbase = W2t; Rin = 512; Cin = 256; c0 = (id & 7) * 32; r0 = (id >> 3) * 64; }
    else return;
  }
  int tx = threadIdx.x & 31, ty = threadIdx.x >> 5;   // ty 0..7
  const float* ip = in + (size_t)(r0 + ty) * Cin + c0 + tx;
#pragma unroll
  for (int i = 0; i < 8; ++i) tile[ty + 8 * i][tx] = ip[(size_t)(8 * i) * Cin];
  __syncthreads();
  int orow = threadIdx.x >> 3;        // 0..31 (input col / node)
  int oseg = (threadIdx.x & 7) * 8;   // 0..56 (input row offset)
  int outrow = c0 + orow;
  if (perm) outrow = rank[(size_t)z * NPB + outrow];
  unsigned short* op = outbase + (size_t)outrow * Rin + r0 + oseg;
  u16x8 o;
#pragma unroll
  for (int k = 0; k < 8; ++k) o[k] = f2bf(tile[oseg + k][orow]);
  *(u16x8*)op = o;
}

// ---- fp32 batched transpose: [B][Rin][Cin] -> [B][Cin][Rin] ----
__global__ void transpose_kernel(const float* __restrict__ in, float* __restrict__ out,
                                 int Rin, int Cin) {
  __shared__ float tile[32][33];
  int c0 = blockIdx.x * 32, r0 = blockIdx.y * 32, b = blockIdx.z;
  int tx = threadIdx.x & 31, ty = threadIdx.x >> 5;
  const float* ip = in + ((size_t)b * Rin + r0) * Cin + c0;
#pragma unroll
  for (int i = 0; i < 32; i += 8) tile[ty + i][tx] = ip[(size_t)(ty + i) * Cin + tx];
  __syncthreads();
  float* op = out + ((size_t)b * Cin + c0) * Rin + r0;
#pragma unroll
  for (int i = 0; i < 32; i += 8) op[(size_t)(ty + i) * Rin + tx] = tile[tx][ty + i];
}

// ---- mask-driven window propagate (bf16 -> bf16), 2 nodes/wave ----
// c(i,q) = mask-bit (i in tgt(q)) + (q==i); mask bits only set for valid q.
__global__ void prop_kernel(const unsigned short* __restrict__ in,
                            unsigned short* __restrict__ out,
                            const unsigned* __restrict__ mask,
                            const float* __restrict__ dinv) {
  int i = blockIdx.x * 8 + (threadIdx.x >> 5);
  int l = threadIdx.x & 31;
  unsigned m = mask[i];
  float a[8] = {};
#pragma unroll
  for (int off = 0; off < 2 * WIN + 1; ++off) {
    int c = ((m >> off) & 1) + (off == WIN);
    if (c) {
      int q = i + off - WIN;
      float dj = (float)c * dinv[q];
      u16x8 u = *(const u16x8*)(in + (size_t)q * 256 + l * 8);
#pragma unroll
      for (int k = 0; k < 8; ++k) a[k] = fmaf(dj, bf2f(u[k]), a[k]);
    }
  }
  float di = dinv[i];
  u16x8 o;
#pragma unroll
  for (int k = 0; k < 8; ++k) o[k] = f2bf(a[k] * di);
  *(u16x8*)(out + (size_t)i * 256 + l * 8) = o;
}

// ---- mask-driven propagate + bias + relu, sorted in -> ORIGINAL-order f32 out ----
__global__ void prop2_kernel(const unsigned short* __restrict__ in,
                             float* __restrict__ out,
                             const unsigned* __restrict__ mask,
                             const float* __restrict__ dinv,
                             const float* __restrict__ bias,
                             const unsigned long long* __restrict__ skeys) {
  int i = blockIdx.x * 8 + (threadIdx.x >> 5);
  int l = threadIdx.x & 31;
  unsigned m = mask[i];
  float a[8] = {};
#pragma unroll
  for (int off = 0; off < 2 * WIN + 1; ++off) {
    int c = ((m >> off) & 1) + (off == WIN);
    if (c) {
      int q = i + off - WIN;
      float dj = (float)c * dinv[q];
      u16x8 u = *(const u16x8*)(in + (size_t)q * 256 + l * 8);
#pragma unroll
      for (int k = 0; k < 8; ++k) a[k] = fmaf(dj, bf2f(u[k]), a[k]);
    }
  }
  float di = dinv[i];
  int node = (i & ~(NPB - 1)) + (int)(skeys[i] & 0xffffffffull);   // un-permute
  float4 o0, o1;
  o0.x = fmaxf(a[0] * di + bias[l * 8 + 0], 0.f);
  o0.y = fmaxf(a[1] * di + bias[l * 8 + 1], 0.f);
  o0.z = fmaxf(a[2] * di + bias[l * 8 + 2], 0.f);
  o0.w = fmaxf(a[3] * di + bias[l * 8 + 3], 0.f);
  o1.x = fmaxf(a[4] * di + bias[l * 8 + 4], 0.f);
  o1.y = fmaxf(a[5] * di + bias[l * 8 + 5], 0.f);
  o1.z = fmaxf(a[6] * di + bias[l * 8 + 6], 0.f);
  o1.w = fmaxf(a[7] * di + bias[l * 8 + 7], 0.f);
  *(float4*)(out + (size_t)node * 256 + l * 8) = o0;
  *(float4*)(out + (size_t)node * 256 + l * 8 + 4) = o1;
}

// ---- bf16 MFMA GEMM: C[M,N] = A[M,K] @ Bt[N,K]^T, 64 x (64*NI) tile ----
template <bool BIAS_RELU, bool OUT_BF16, int NI>
__global__ __launch_bounds__(256)
void gemm_bf16_kernel(const unsigned short* __restrict__ A,
                      const unsigned short* __restrict__ Bt,
                      void* __restrict__ C, const float* __restrict__ bias,
                      int M, int N, int K) {
  __shared__ char lds[8192 + NI * 8192];   // A: [64][128B] @0 ; B: [64*NI][128B] @8192
  const int tid = threadIdx.x;
  const int l = tid & 63, w = tid >> 6;
  const int bm = blockIdx.x * 64, bn = blockIdx.y * (64 * NI);
  f32x4 acc[4][NI] = {};

  for (int k0 = 0; k0 < K; k0 += 64) {
    __syncthreads();
#pragma unroll
    for (int q = 0; q < 2; ++q) {          // A tile: 8KB
      int o = q * 4096 + tid * 16;
      int r = o >> 7;
      int gc = ((o >> 4) & 7) ^ (r & 7);
      const char* srcA = (const char*)A + ((size_t)(bm + r) * K + k0) * 2 + gc * 16;
      __builtin_amdgcn_global_load_lds(
          (const __attribute__((address_space(1))) void*)srcA,
          (__attribute__((address_space(3))) void*)(lds + o), 16, 0, 0);
    }
#pragma unroll
    for (int q = 0; q < 2 * NI; ++q) {     // B tile: NI*8KB
      int o = q * 4096 + tid * 16;
      int r = o >> 7;
      int gc = ((o >> 4) & 7) ^ (r & 7);
      const char* srcB = (const char*)Bt + ((size_t)(bn + r) * K + k0) * 2 + gc * 16;
      __builtin_amdgcn_global_load_lds(
          (const __attribute__((address_space(1))) void*)srcB,
          (__attribute__((address_space(3))) void*)(lds + 8192 + o), 16, 0, 0);
    }
    __syncthreads();

#pragma unroll
    for (int kk = 0; kk < 64; kk += 32) {
      bf16x8 af[4], bf[NI];
      int gc = (kk >> 3) + (l >> 4);
#pragma unroll
      for (int mi = 0; mi < 4; ++mi) {
        int r = mi * 16 + (l & 15);
        af[mi] = *(const bf16x8*)(lds + r * 128 + ((gc ^ (r & 7)) << 4));
      }
#pragma unroll
      for (int ni = 0; ni < NI; ++ni) {
        int r = w * (16 * NI) + ni * 16 + (l & 15);
        bf[ni] = *(const bf16x8*)(lds + 8192 + r * 128 + ((gc ^ (r & 7)) << 4));
      }
#pragma unroll
      for (int mi = 0; mi < 4; ++mi)
#pragma unroll
        for (int ni = 0; ni < NI; ++ni)
          acc[mi][ni] = __builtin_amdgcn_mfma_f32_16x16x32_bf16(af[mi], bf[ni],
                                                                acc[mi][ni], 0, 0, 0);
    }
  }

#pragma unroll
  for (int mi = 0; mi < 4; ++mi) {
#pragma unroll
    for (int ni = 0; ni < NI; ++ni) {
      int row0 = bm + mi * 16 + ((l >> 4) << 2);
      int col = bn + w * (16 * NI) + ni * 16 + (l & 15);
      float bv = BIAS_RELU ? bias[col] : 0.f;
      f32x4 v = acc[mi][ni];
#pragma unroll
      for (int r = 0; r < 4; ++r) {
        float val = v[r];
        if (BIAS_RELU) val = fmaxf(val + bv, 0.f);
        if (OUT_BF16)
          ((unsigned short*)C)[(size_t)(row0 + r) * N + col] = f2bf(val);
        else
          ((float*)C)[(size_t)(row0 + r) * N + col] = val;
      }
    }
  }
}

// ---- launch ----
extern "C" void kernel_launch(void* const* d_in, const int* in_sizes, int n_in,
                              void* d_out, int out_size, void* d_ws, size_t ws_size,
                              hipStream_t stream) {
  const float* dm = (const float*)d_in[0];
  const float* fm = (const float*)d_in[1];
  const float* W1 = (const float*)d_in[2];
  const float* b1 = (const float*)d_in[3];
  const float* W2 = (const float*)d_in[4];
  const float* b2 = (const float*)d_in[5];
  float* out = (float*)d_out;

  char* ws = (char*)d_ws;
  float*              dinv  = (float*)(ws + 0x050000);             // 64KB
  unsigned*           mask  = (unsigned*)(ws + 0x060000);          // 64KB
  unsigned long long* skeys = (unsigned long long*)(ws + 0x100000);// 128KB
  int*                rank  = (int*)(ws + 0x130000);               // 64KB
  unsigned short*     W1t   = (unsigned short*)(ws + 0x190000);    // 256KB
  unsigned short*     W2t   = (unsigned short*)(ws + 0x1D0000);    // 256KB
  unsigned short*     px0   = (unsigned short*)(ws + 0x0400000);   // 8MB (sorted space)
  unsigned short*     px    = (unsigned short*)(ws + 0x0C00000);   // 8MB (sorted space)
  unsigned short*     h1    = (unsigned short*)(ws + 0x1400000);   // 16MB (sorted space)
  unsigned short*     t2    = (unsigned short*)(ws + 0x2400000);   // 8MB (sorted space)
  float*              xout  = (float*)(ws + 0x2C00000);            // 16MB (original order)
  (void)ws_size; (void)in_sizes; (void)n_in; (void)out_size;

  // ---- graph build: ONE kernel (sort + select + deg + edge masks) ----
  bucket_kernel<<<NB, 1024, 0, stream>>>(dm, skeys, rank, dinv, mask);

  // ---- conversions: fm -> sorted-space bf16 rows; weights -> [N][K] bf16 ----
  cvt_all_kernel<<<dim3(128, 4, NB + 1), 256, 0, stream>>>(fm, px0, W1, W1t, W2, W2t, rank);

  // layer 1 (sorted space): mask propagate, then GEMM relu(.@W1+b1) -> bf16
  prop_kernel<<<N_NODES / 8, 256, 0, stream>>>(px0, px, mask, dinv);
  gemm_bf16_kernel<true, true, 1><<<dim3(256, 8), 256, 0, stream>>>(
      px, W1t, h1, b1, 16384, 512, 256);

  // layer 2: GEMM h1@W2 -> bf16, mask propagate + un-permute -> f32
  gemm_bf16_kernel<false, true, 1><<<dim3(256, 4), 256, 0, stream>>>(
      h1, W2t, t2, nullptr, 16384, 256, 512);
  prop2_kernel<<<N_NODES / 8, 256, 0, stream>>>(t2, xout, mask, dinv, b2, skeys);

  // node-major -> [B][256][4096]
  transpose_kernel<<<dim3(8, 128, NB), 256, 0, stream>>>(xout, out, 4096, 256);
}